// Round 10
// baseline (116.980 us; speedup 1.0000x reference)
//
#include <hip/hip_runtime.h>
#include <stdint.h>

typedef __attribute__((ext_vector_type(8))) short short8;
typedef __attribute__((ext_vector_type(4))) float f32x4;
typedef __attribute__((ext_vector_type(8))) unsigned short ushort8;
typedef __attribute__((ext_vector_type(4))) unsigned short ushort4v;

__device__ __forceinline__ unsigned short f2bf(float f) {
  uint32_t u = __float_as_uint(f);
  uint32_t r = (u + 0x7fffu + ((u >> 16) & 1u)) >> 16;  // RNE
  return (unsigned short)r;
}
__device__ __forceinline__ float bf2f(unsigned short v) {
  return __uint_as_float(((uint32_t)v) << 16);
}

typedef __attribute__((address_space(1))) const unsigned int g_u32;
typedef __attribute__((address_space(3))) unsigned int l_u32;
__device__ __forceinline__ void gl_lds16(const void* g, void* l) {
  __builtin_amdgcn_global_load_lds((g_u32*)g, (l_u32*)l, 16, 0, 0);
}

// ---------------- Threefry-2x32-20 (exact JAX partitionable semantics) ----------------
__device__ __forceinline__ uint32_t rotl32(uint32_t v, int d) { return (v << d) | (v >> (32 - d)); }

__device__ __forceinline__ void threefry2x32(uint32_t k0, uint32_t k1, uint32_t& x0, uint32_t& x1) {
  const uint32_t ks2 = k0 ^ k1 ^ 0x1BD11BDAu;
  x0 += k0; x1 += k1;
  x0 += x1; x1 = rotl32(x1, 13); x1 ^= x0;
  x0 += x1; x1 = rotl32(x1, 15); x1 ^= x0;
  x0 += x1; x1 = rotl32(x1, 26); x1 ^= x0;
  x0 += x1; x1 = rotl32(x1, 6);  x1 ^= x0;
  x0 += k1; x1 += ks2 + 1u;
  x0 += x1; x1 = rotl32(x1, 17); x1 ^= x0;
  x0 += x1; x1 = rotl32(x1, 29); x1 ^= x0;
  x0 += x1; x1 = rotl32(x1, 16); x1 ^= x0;
  x0 += x1; x1 = rotl32(x1, 24); x1 ^= x0;
  x0 += ks2; x1 += k0 + 2u;
  x0 += x1; x1 = rotl32(x1, 13); x1 ^= x0;
  x0 += x1; x1 = rotl32(x1, 15); x1 ^= x0;
  x0 += x1; x1 = rotl32(x1, 26); x1 ^= x0;
  x0 += x1; x1 = rotl32(x1, 6);  x1 ^= x0;
  x0 += k0; x1 += k1 + 3u;
  x0 += x1; x1 = rotl32(x1, 17); x1 ^= x0;
  x0 += x1; x1 = rotl32(x1, 29); x1 ^= x0;
  x0 += x1; x1 = rotl32(x1, 16); x1 ^= x0;
  x0 += x1; x1 = rotl32(x1, 24); x1 ^= x0;
  x0 += k1; x1 += ks2 + 4u;
  x0 += x1; x1 = rotl32(x1, 13); x1 ^= x0;
  x0 += x1; x1 = rotl32(x1, 15); x1 ^= x0;
  x0 += x1; x1 = rotl32(x1, 26); x1 ^= x0;
  x0 += x1; x1 = rotl32(x1, 6);  x1 ^= x0;
  x0 += ks2; x1 += k0 + 5u;
}

// ---------------- prep: cast z->bf16 | transpose+cast W1,WR | decode prog ----------------
__global__ __launch_bounds__(256) void prep_kernel(const float* __restrict__ z,
                                                   unsigned short* __restrict__ zb, int n8,
                                                   const float* __restrict__ W1,
                                                   const float* __restrict__ WR,
                                                   unsigned short* __restrict__ W1t,
                                                   unsigned short* __restrict__ WRt,
                                                   const float* __restrict__ P_op,
                                                   const float* __restrict__ P_dst,
                                                   const float* __restrict__ P_s1,
                                                   const float* __restrict__ P_s2,
                                                   const float* __restrict__ P_imm,
                                                   const float* __restrict__ Plen,
                                                   float* __restrict__ prog,
                                                   float* __restrict__ plen, int BT) {
  __shared__ float t[32][33];
  const int tid = threadIdx.x;
  const int bx = blockIdx.x;
  if (bx < 2048) {
    const int i = bx * 256 + tid;
    if (i >= n8) return;
    const float4 a = reinterpret_cast<const float4*>(z)[i * 2];
    const float4 b = reinterpret_cast<const float4*>(z)[i * 2 + 1];
    ushort8 u;
    u[0] = f2bf(a.x); u[1] = f2bf(a.y); u[2] = f2bf(a.z); u[3] = f2bf(a.w);
    u[4] = f2bf(b.x); u[5] = f2bf(b.y); u[6] = f2bf(b.z); u[7] = f2bf(b.w);
    reinterpret_cast<ushort8*>(zb)[i] = u;
  } else if (bx < 2688) {
    const int b = bx - 2048;
    const float* src; unsigned short* dst; int N, K, k0, n0;
    if (b < 512) {
      src = W1; dst = W1t; N = 1024; K = 512;
      k0 = (b & 15) * 32; n0 = (b >> 4) * 32;
    } else {
      const int b2 = b - 512;
      src = WR; dst = WRt; N = 128; K = 1024;
      k0 = (b2 & 31) * 32; n0 = (b2 >> 5) * 32;
    }
    {
      const int row = tid >> 3, c4 = (tid & 7) * 4;
      const float4 v = *reinterpret_cast<const float4*>(&src[(size_t)(k0 + row) * N + n0 + c4]);
      t[row][c4] = v.x; t[row][c4 + 1] = v.y; t[row][c4 + 2] = v.z; t[row][c4 + 3] = v.w;
    }
    __syncthreads();
    {
      const int n = tid >> 3, k4 = (tid & 7) * 4;
      ushort4v o;
      o.x = f2bf(t[k4 + 0][n]); o.y = f2bf(t[k4 + 1][n]);
      o.z = f2bf(t[k4 + 2][n]); o.w = f2bf(t[k4 + 3][n]);
      *reinterpret_cast<ushort4v*>(&dst[(size_t)(n0 + n) * K + k0 + k4]) = o;
    }
  } else {
    const int i = (bx - 2688) * 256 + tid;
    if (i >= BT) return;
    const float* po = P_op + (size_t)i * 4;
    const float op = po[0] + 2.f * po[1] + 4.f * po[2] + 8.f * po[3];
    const float* pd = P_dst + (size_t)i * 3;
    const float dv = pd[0] + 2.f * pd[1] + 4.f * pd[2];
    const float* p1 = P_s1 + (size_t)i * 3;
    const float s1v = p1[0] + 2.f * p1[1] + 4.f * p1[2];
    const float* p2 = P_s2 + (size_t)i * 3;
    const float s2v = p2[0] + 2.f * p2[1] + 4.f * p2[2];
    const float* pi = P_imm + (size_t)i * 3;
    const float imv = pi[0] + 2.f * pi[1] + 4.f * pi[2];
    float* o = prog + (size_t)i * 5;
    o[0] = op; o[1] = dv; o[2] = s1v; o[3] = s2v; o[4] = imv;
    if ((i & 15) == 0) {
      const int b = i >> 4;
      const float* pl = Plen + (size_t)b * 4;
      plen[b] = pl[0] + 2.f * pl[1] + 4.f * pl[2] + 8.f * pl[3];
    }
  }
}

// ---------------- GEMM1 only: h = relu(zb @ W1t + b1) -> bf16 global ----------------
__global__ __launch_bounds__(256) void gemm1_kernel(const unsigned short* __restrict__ zb,
                                                    const unsigned short* __restrict__ W1t,
                                                    const float* __restrict__ b1,
                                                    unsigned short* __restrict__ h) {
  __shared__ __align__(16) char smem[34816];
  unsigned short* AsF = (unsigned short*)smem;            // [128][64] swizzled
  unsigned short* BsF = (unsigned short*)(smem + 16384);  // [128][64] swizzled
  auto H2 = reinterpret_cast<unsigned short (*)[136]>(smem);

  const int tid = threadIdx.x;
  const int lane = tid & 63, wave = tid >> 6;
  const int wm = wave >> 1, wn = wave & 1;
  const int bm = blockIdx.y * 128, bn = blockIdx.x * 128;

  f32x4 acc[4][4];
#pragma unroll
  for (int i = 0; i < 4; ++i)
#pragma unroll
    for (int j = 0; j < 4; ++j) acc[i][j] = (f32x4)0.f;

  const int fr = lane & 15;
  const int lr = (lane >> 4) * 4, lc = lane & 15;
  const int lrow = lane >> 3, slot = lane & 7;
  const int sslot = (slot ^ lrow) << 3;
  const int fx = fr & 7;
  const int cbase = lane >> 4;

  for (int k0 = 0; k0 < 512; k0 += 64) {
#pragma unroll
    for (int i = 0; i < 4; ++i) {
      const int r0 = wave * 32 + i * 8;
      gl_lds16(&zb[(size_t)(bm + r0 + lrow) * 512 + k0 + sslot], &AsF[r0 * 64]);
    }
#pragma unroll
    for (int i = 0; i < 4; ++i) {
      const int r0 = wave * 32 + i * 8;
      gl_lds16(&W1t[(size_t)(bn + r0 + lrow) * 512 + k0 + sslot], &BsF[r0 * 64]);
    }
    __syncthreads();
#pragma unroll
    for (int s = 0; s < 2; ++s) {
      short8 af[4], bfv[4];
#pragma unroll
      for (int f = 0; f < 4; ++f) {
        const int row = wm * 64 + f * 16 + fr;
        const int c = s * 4 + cbase;
        af[f] = *reinterpret_cast<const short8*>(&AsF[row * 64 + ((c ^ fx) << 3)]);
      }
#pragma unroll
      for (int f = 0; f < 4; ++f) {
        const int row = wn * 64 + f * 16 + fr;
        const int c = s * 4 + cbase;
        bfv[f] = *reinterpret_cast<const short8*>(&BsF[row * 64 + ((c ^ fx) << 3)]);
      }
#pragma unroll
      for (int fm = 0; fm < 4; ++fm)
#pragma unroll
        for (int fn = 0; fn < 4; ++fn)
          acc[fm][fn] = __builtin_amdgcn_mfma_f32_16x16x32_bf16(af[fm], bfv[fn], acc[fm][fn], 0, 0, 0);
    }
    __syncthreads();
  }

  // epilogue -> H2 -> coalesced global h
#pragma unroll
  for (int fn = 0; fn < 4; ++fn) {
    const int col_l = wn * 64 + fn * 16 + lc;
    const float bv = b1[bn + col_l];
#pragma unroll
    for (int fm = 0; fm < 4; ++fm) {
      const int row_l0 = wm * 64 + fm * 16 + lr;
#pragma unroll
      for (int r = 0; r < 4; ++r)
        H2[row_l0 + r][col_l] = f2bf(fmaxf(acc[fm][fn][r] + bv, 0.f));
    }
  }
  __syncthreads();
  {
    const int row = tid >> 1, c0 = (tid & 1) * 64;
    unsigned short* hp = &h[(size_t)(bm + row) * 1024 + bn + c0];
#pragma unroll
    for (int j = 0; j < 8; ++j)
      *reinterpret_cast<ushort8*>(hp + j * 8) = *reinterpret_cast<const ushort8*>(&H2[row][c0 + j * 8]);
  }
}

// ---------------- scan3: h-tile -> GEMM2(MFMA) + sigmoid + thresh + soft-VM scan [+ expand] ----------------
template <bool FUSE>
__global__ __launch_bounds__(256) void scan3_kernel(const unsigned short* __restrict__ h,
                                                    const unsigned short* __restrict__ WRt,
                                                    const float* __restrict__ bR,
                                                    const float* __restrict__ Wt,
                                                    const float* __restrict__ bt,
                                                    const float* __restrict__ prog,
                                                    const float* __restrict__ plen,
                                                    const float* __restrict__ W,
                                                    const float* __restrict__ bias,
                                                    const float* __restrict__ gam,
                                                    const float* __restrict__ bet,
                                                    float* __restrict__ Rfinal,
                                                    float* __restrict__ thr_out,
                                                    float* __restrict__ out) {
  __shared__ __align__(16) char arena[46400];
  auto h_lds = reinterpret_cast<unsigned short (*)[1032]>(arena);   // 16 x 1032 shorts (pad: 2-way-free frag reads)
  float* sb = reinterpret_cast<float*>(arena + 33024);              // s_bits [16][128] / later Rs[256][8]
  float* sp = reinterpret_cast<float*>(arena + 41216);              // s_prog [16][80]
  float* spl = reinterpret_cast<float*>(arena + 46336);             // [16]

  const int tid = threadIdx.x;
  const int lane = tid & 63, wave = tid >> 6;
  const int b0 = blockIdx.x * 16;

  // load h rows for 16 batches
#pragma unroll
  for (int j = 0; j < 8; ++j) {
    const int idx = tid + 256 * j;       // 0..2047, 128 chunks/row
    const int row = idx >> 7, seg = idx & 127;
    *reinterpret_cast<ushort8*>(&h_lds[row][seg * 8]) =
        *reinterpret_cast<const ushort8*>(&h[(size_t)(b0 + row) * 1024 + seg * 8]);
  }
#pragma unroll
  for (int j = 0; j < 5; ++j) {
    const int f = tid + 256 * j;
    sp[f] = prog[(size_t)b0 * 80 + f];
  }
  if (tid < 16) spl[tid] = plen[b0 + tid];
  __syncthreads();

  // GEMM2: M=16 (batches), N=128, K=1024; 2 n-frags per wave
  {
    f32x4 acc0 = (f32x4)0.f, acc1 = (f32x4)0.f;
    const int fr = lane & 15, khi = (lane >> 4) * 8;
    const int n0 = wave * 32;
#pragma unroll
    for (int k0 = 0; k0 < 1024; k0 += 32) {
      const short8 af = *reinterpret_cast<const short8*>(&h_lds[fr][k0 + khi]);
      const short8 bf0 = *reinterpret_cast<const short8*>(&WRt[(size_t)(n0 + fr) * 1024 + k0 + khi]);
      const short8 bf1 = *reinterpret_cast<const short8*>(&WRt[(size_t)(n0 + 16 + fr) * 1024 + k0 + khi]);
      acc0 = __builtin_amdgcn_mfma_f32_16x16x32_bf16(af, bf0, acc0, 0, 0, 0);
      acc1 = __builtin_amdgcn_mfma_f32_16x16x32_bf16(af, bf1, acc1, 0, 0, 0);
    }
    // D: col = lane&15, row = (lane>>4)*4 + r
    const int col0 = n0 + (lane & 15), col1 = n0 + 16 + (lane & 15);
    const float bb0 = bR[col0], bb1 = bR[col1];
#pragma unroll
    for (int r = 0; r < 4; ++r) {
      const int row = (lane >> 4) * 4 + r;
      sb[row * 128 + col0] = 1.f / (1.f + expf(-(acc0[r] + bb0)));
      sb[row * 128 + col1] = 1.f / (1.f + expf(-(acc1[r] + bb1)));
    }
  }

  // threshold: thread t -> batch t>>4, segment (t&15)*64
  {
    const int lb = tid >> 4, sg = (tid & 15) * 64;
    float s = 0.f;
#pragma unroll
    for (int j = 0; j < 8; ++j) {
      const ushort8 a = *reinterpret_cast<const ushort8*>(&h_lds[lb][sg + j * 8]);
      const float4 w0 = *reinterpret_cast<const float4*>(&Wt[sg + j * 8]);
      const float4 w1 = *reinterpret_cast<const float4*>(&Wt[sg + j * 8 + 4]);
      s += bf2f(a[0]) * w0.x + bf2f(a[1]) * w0.y + bf2f(a[2]) * w0.z + bf2f(a[3]) * w0.w;
      s += bf2f(a[4]) * w1.x + bf2f(a[5]) * w1.y + bf2f(a[6]) * w1.z + bf2f(a[7]) * w1.w;
    }
    s += __shfl_xor(s, 1); s += __shfl_xor(s, 2); s += __shfl_xor(s, 4); s += __shfl_xor(s, 8);
    if ((tid & 15) == 0) thr_out[b0 + lb] = 1.f / (1.f + expf(-(s + bt[0])));
  }
  __syncthreads();

  // ---- soft-VM scan ----
  const int lb = tid >> 4, g = tid & 15;
  const int bg = (b0 + lb) * 16 + g;

  uint32_t k2a, k2b;
  { uint32_t x0 = 0u, x1 = 1u; threefry2x32(0u, 42u, x0, x1); k2a = x0; k2b = x1; }
  uint32_t p0, p1;
  {
    uint32_t x0 = 0u, x1 = (uint32_t)bg * 2u;
    threefry2x32(k2a, k2b, x0, x1);
    p0 = (x0 ^ x1) & 127u;
  }
  {
    uint32_t x0 = 0u, x1 = (uint32_t)bg * 2u + 1u;
    threefry2x32(k2a, k2b, x0, x1);
    p1 = (x0 ^ x1) & 127u;
  }

  float R[8], M[8];
#pragma unroll
  for (int r = 0; r < 8; ++r) {
    float a = 0.f;
#pragma unroll
    for (int bit = 0; bit < 16; ++bit) {
      const int pos = r * 16 + bit;
      float v = sb[lb * 128 + pos];
      const bool flip = (g != 0) && ((int)p0 == pos || (int)p1 == pos);
      v = flip ? 1.0f - v : v;
      a = fmaf(v, (float)(1 << bit), a);
    }
    R[r] = a;
    M[r] = 0.f;
  }

  const float pl = spl[lb];
  for (int t = 0; t < 16; ++t) {
    const float op = sp[lb * 80 + t * 5 + 0];
    const float dst = sp[lb * 80 + t * 5 + 1];
    const float sa = sp[lb * 80 + t * 5 + 2];
    const float sbv = sp[lb * 80 + t * 5 + 3];
    const float imm = sp[lb * 80 + t * 5 + 4];
    const float active = fminf(fmaxf(pl - (float)t, 0.f), 1.f);
    float r1 = 0.f, r2 = 0.f, m1 = 0.f, old = 0.f;
    float wd[8];
#pragma unroll
    for (int i = 0; i < 8; ++i) {
      const float w1 = fmaxf(1.f - fabsf(sa - (float)i), 0.f);
      const float w2 = fmaxf(1.f - fabsf(sbv - (float)i), 0.f);
      wd[i] = fmaxf(1.f - fabsf(dst - (float)i), 0.f);
      r1 = fmaf(w1, R[i], r1);
      r2 = fmaf(w2, R[i], r2);
      m1 = fmaf(w1, M[i], m1);
      old = fmaf(wd[i], R[i], old);
    }
    float results[16];
    results[0] = old;               results[1] = r1 + r2;
    results[2] = r1 - r2;           results[3] = r1 * r2 * (1.f / 65536.f);
    results[4] = r1;                results[5] = imm;
    results[6] = r1 + imm;          results[7] = fmaxf(r1, r2);
    results[8] = fminf(r1, r2);     results[9] = -r1;
    results[10] = 0.5f * r1;        results[11] = r2;
    results[12] = m1;               results[13] = old;
    results[14] = fabsf(r1);        results[15] = old;
    float res = 0.f;
    const float pstore = fmaxf(1.f - fabsf(op - 13.f), 0.f);
#pragma unroll
    for (int o = 0; o < 16; ++o) res = fmaf(fmaxf(1.f - fabsf(op - (float)o), 0.f), results[o], res);
#pragma unroll
    for (int i = 0; i < 8; ++i) {
      R[i] = fmaf(active * wd[i], res - R[i], R[i]);
      M[i] = fmaf(active * pstore * wd[i], r1 - M[i], M[i]);
    }
  }

  if (!FUSE) {
    float* outp = Rfinal + (size_t)bg * 8;
#pragma unroll
    for (int r = 0; r < 8; ++r) outp[r] = R[r];
    return;
  }

  // ---- fused expand: R -> LDS handoff, per-wave W regs, 64 rows/wave ----
  __syncthreads();                      // all sb reads done
  float* Rs = sb;                       // [256][8] overlay
#pragma unroll
  for (int r = 0; r < 8; ++r) Rs[tid * 8 + r] = R[r];
  __syncthreads();

  const int h0 = lane * 8;
  float wreg[8][8];
#pragma unroll
  for (int reg = 0; reg < 8; ++reg) {
    const float4 wa = *reinterpret_cast<const float4*>(&W[reg * 512 + h0]);
    const float4 wb = *reinterpret_cast<const float4*>(&W[reg * 512 + h0 + 4]);
    wreg[reg][0] = wa.x; wreg[reg][1] = wa.y; wreg[reg][2] = wa.z; wreg[reg][3] = wa.w;
    wreg[reg][4] = wb.x; wreg[reg][5] = wb.y; wreg[reg][6] = wb.z; wreg[reg][7] = wb.w;
  }
  float bi[8], ga[8], be[8];
  {
    const float4 a = *reinterpret_cast<const float4*>(&bias[h0]);
    const float4 b = *reinterpret_cast<const float4*>(&bias[h0 + 4]);
    bi[0] = a.x; bi[1] = a.y; bi[2] = a.z; bi[3] = a.w; bi[4] = b.x; bi[5] = b.y; bi[6] = b.z; bi[7] = b.w;
    const float4 c = *reinterpret_cast<const float4*>(&gam[h0]);
    const float4 d = *reinterpret_cast<const float4*>(&gam[h0 + 4]);
    ga[0] = c.x; ga[1] = c.y; ga[2] = c.z; ga[3] = c.w; ga[4] = d.x; ga[5] = d.y; ga[6] = d.z; ga[7] = d.w;
    const float4 e = *reinterpret_cast<const float4*>(&bet[h0]);
    const float4 f = *reinterpret_cast<const float4*>(&bet[h0 + 4]);
    be[0] = e.x; be[1] = e.y; be[2] = e.z; be[3] = e.w; be[4] = f.x; be[5] = f.y; be[6] = f.z; be[7] = f.w;
  }

  const size_t rbase = (size_t)b0 * 16;
  for (int i = 0; i < 64; ++i) {
    const int rl = wave * 64 + i;
    const float4 ra = *reinterpret_cast<const float4*>(&Rs[rl * 8]);
    const float4 rb = *reinterpret_cast<const float4*>(&Rs[rl * 8 + 4]);
    const float rr[8] = {ra.x, ra.y, ra.z, ra.w, rb.x, rb.y, rb.z, rb.w};
    float x[8];
#pragma unroll
    for (int j = 0; j < 8; ++j) x[j] = bi[j];
#pragma unroll
    for (int reg = 0; reg < 8; ++reg)
#pragma unroll
      for (int j = 0; j < 8; ++j) x[j] = fmaf(rr[reg], wreg[reg][j], x[j]);
    float s1 = 0.f, s2 = 0.f;
#pragma unroll
    for (int j = 0; j < 8; ++j) { s1 += x[j]; s2 = fmaf(x[j], x[j], s2); }
#pragma unroll
    for (int off = 32; off; off >>= 1) { s1 += __shfl_xor(s1, off); s2 += __shfl_xor(s2, off); }
    const float mean = s1 * (1.f / 512.f);
    const float var = s2 * (1.f / 512.f) - mean * mean;
    const float inv = rsqrtf(var + 1e-5f);
    float y[8];
#pragma unroll
    for (int j = 0; j < 8; ++j) y[j] = (x[j] - mean) * inv * ga[j] + be[j];
    float* dst = out + (rbase + rl) * 512 + h0;
    *reinterpret_cast<float4*>(dst) = make_float4(y[0], y[1], y[2], y[3]);
    *reinterpret_cast<float4*>(dst + 4) = make_float4(y[4], y[5], y[6], y[7]);
  }
}

// ---------------- standalone expand (fallback path) ----------------
__global__ __launch_bounds__(256) void final_expand2(const float* __restrict__ Rf,
                                                     const float* __restrict__ W,
                                                     const float* __restrict__ bias,
                                                     const float* __restrict__ gam,
                                                     const float* __restrict__ bet,
                                                     float* __restrict__ out, int rowsPerWave) {
  const int lane = threadIdx.x & 63;
  const int w = blockIdx.x * 4 + (threadIdx.x >> 6);
  const int h0 = lane * 8;

  float wreg[8][8];
#pragma unroll
  for (int reg = 0; reg < 8; ++reg) {
    const float4 wa = *reinterpret_cast<const float4*>(&W[reg * 512 + h0]);
    const float4 wb = *reinterpret_cast<const float4*>(&W[reg * 512 + h0 + 4]);
    wreg[reg][0] = wa.x; wreg[reg][1] = wa.y; wreg[reg][2] = wa.z; wreg[reg][3] = wa.w;
    wreg[reg][4] = wb.x; wreg[reg][5] = wb.y; wreg[reg][6] = wb.z; wreg[reg][7] = wb.w;
  }
  float bi[8], ga[8], be[8];
  {
    const float4 a = *reinterpret_cast<const float4*>(&bias[h0]);
    const float4 b = *reinterpret_cast<const float4*>(&bias[h0 + 4]);
    bi[0] = a.x; bi[1] = a.y; bi[2] = a.z; bi[3] = a.w; bi[4] = b.x; bi[5] = b.y; bi[6] = b.z; bi[7] = b.w;
    const float4 c = *reinterpret_cast<const float4*>(&gam[h0]);
    const float4 d = *reinterpret_cast<const float4*>(&gam[h0 + 4]);
    ga[0] = c.x; ga[1] = c.y; ga[2] = c.z; ga[3] = c.w; ga[4] = d.x; ga[5] = d.y; ga[6] = d.z; ga[7] = d.w;
    const float4 e = *reinterpret_cast<const float4*>(&bet[h0]);
    const float4 f = *reinterpret_cast<const float4*>(&bet[h0 + 4]);
    be[0] = e.x; be[1] = e.y; be[2] = e.z; be[3] = e.w; be[4] = f.x; be[5] = f.y; be[6] = f.z; be[7] = f.w;
  }

  const int r0 = w * rowsPerWave;
  for (int i = 0; i < rowsPerWave; ++i) {
    const int row = r0 + i;
    const float4 ra = *reinterpret_cast<const float4*>(&Rf[(size_t)row * 8]);
    const float4 rb = *reinterpret_cast<const float4*>(&Rf[(size_t)row * 8 + 4]);
    const float r[8] = {ra.x, ra.y, ra.z, ra.w, rb.x, rb.y, rb.z, rb.w};
    float x[8];
#pragma unroll
    for (int j = 0; j < 8; ++j) x[j] = bi[j];
#pragma unroll
    for (int reg = 0; reg < 8; ++reg)
#pragma unroll
      for (int j = 0; j < 8; ++j) x[j] = fmaf(r[reg], wreg[reg][j], x[j]);
    float s1 = 0.f, s2 = 0.f;
#pragma unroll
    for (int j = 0; j < 8; ++j) { s1 += x[j]; s2 = fmaf(x[j], x[j], s2); }
#pragma unroll
    for (int off = 32; off; off >>= 1) { s1 += __shfl_xor(s1, off); s2 += __shfl_xor(s2, off); }
    const float mean = s1 * (1.f / 512.f);
    const float var = s2 * (1.f / 512.f) - mean * mean;
    const float inv = rsqrtf(var + 1e-5f);
    float y[8];
#pragma unroll
    for (int j = 0; j < 8; ++j) y[j] = (x[j] - mean) * inv * ga[j] + be[j];
    float* dst = out + (size_t)row * 512 + h0;
    *reinterpret_cast<float4*>(dst) = make_float4(y[0], y[1], y[2], y[3]);
    *reinterpret_cast<float4*>(dst + 4) = make_float4(y[4], y[5], y[6], y[7]);
  }
}

// ---------------- launch ----------------
extern "C" void kernel_launch(void* const* d_in, const int* in_sizes, int n_in,
                              void* d_out, int out_size, void* d_ws, size_t ws_size,
                              hipStream_t stream) {
  const float* z    = (const float*)d_in[0];
  const float* P_op = (const float*)d_in[1];
  const float* P_dst= (const float*)d_in[2];
  const float* P_s1 = (const float*)d_in[3];
  const float* P_s2 = (const float*)d_in[4];
  const float* P_imm= (const float*)d_in[5];
  const float* Plen = (const float*)d_in[6];
  const float* W1   = (const float*)d_in[8];
  const float* b1   = (const float*)d_in[9];
  const float* WR   = (const float*)d_in[10];
  const float* bR   = (const float*)d_in[11];
  const float* Wt   = (const float*)d_in[12];
  const float* bt   = (const float*)d_in[13];
  const float* W_r2h= (const float*)d_in[14];
  const float* b_r2h= (const float*)d_in[15];
  const float* ln_g = (const float*)d_in[16];
  const float* ln_b = (const float*)d_in[17];

  const int B = in_sizes[0] / 512;  // 8192
  float* out = (float*)d_out;
  float* thr_out = out + (size_t)B * 16 * 512;

  float* ws = (float*)d_ws;
  float* prog   = ws;                                  // B*80
  float* plen   = prog + (size_t)B * 80;               // B
  float* Rfinal = plen + B;                            // B*128 (fallback only)
  unsigned short* W1t = (unsigned short*)(Rfinal + (size_t)B * 128);
  unsigned short* WRt = W1t + (size_t)1024 * 512;
  unsigned short* zb  = WRt + (size_t)128 * 1024;      // B*512 shorts
  unsigned short* h_ws = zb + (size_t)B * 512;         // B*1024 shorts (fused path)

  const size_t need = (size_t)((char*)(h_ws + (size_t)B * 1024) - (char*)d_ws);
  const bool fuse = ws_size >= need;
  unsigned short* h = fuse ? h_ws : (unsigned short*)(out + (size_t)(1 << 25));

  const dim3 blk(256);
  prep_kernel<<<dim3(3200), blk, 0, stream>>>(z, zb, B * 512 / 8, W1, WR, W1t, WRt,
                                              P_op, P_dst, P_s1, P_s2, P_imm, Plen,
                                              prog, plen, B * 16);
  gemm1_kernel<<<dim3(8, B / 128), blk, 0, stream>>>(zb, W1t, b1, h);
  if (fuse) {
    scan3_kernel<true><<<dim3(B / 16), blk, 0, stream>>>(h, WRt, bR, Wt, bt, prog, plen,
                                                         W_r2h, b_r2h, ln_g, ln_b,
                                                         Rfinal, thr_out, out);
  } else {
    scan3_kernel<false><<<dim3(B / 16), blk, 0, stream>>>(h, WRt, bR, Wt, bt, prog, plen,
                                                          W_r2h, b_r2h, ln_g, ln_b,
                                                          Rfinal, thr_out, out);
    final_expand2<<<dim3(B * 16 / 4 / 32), blk, 0, stream>>>(Rfinal, W_r2h, b_r2h, ln_g, ln_b,
                                                             out, 32);
  }
}

// Round 11
// 111.949 us; speedup vs baseline: 1.0449x; 1.0449x over previous
//
#include <hip/hip_runtime.h>
#include <stdint.h>

typedef __attribute__((ext_vector_type(8))) short short8;
typedef __attribute__((ext_vector_type(4))) float f32x4;
typedef __attribute__((ext_vector_type(8))) unsigned short ushort8;
typedef __attribute__((ext_vector_type(4))) unsigned short ushort4v;

__device__ __forceinline__ unsigned short f2bf(float f) {
  uint32_t u = __float_as_uint(f);
  uint32_t r = (u + 0x7fffu + ((u >> 16) & 1u)) >> 16;  // RNE
  return (unsigned short)r;
}
__device__ __forceinline__ float bf2f(unsigned short v) {
  return __uint_as_float(((uint32_t)v) << 16);
}

typedef __attribute__((address_space(1))) const unsigned int g_u32;
typedef __attribute__((address_space(3))) unsigned int l_u32;
__device__ __forceinline__ void gl_lds16(const void* g, void* l) {
  __builtin_amdgcn_global_load_lds((g_u32*)g, (l_u32*)l, 16, 0, 0);
}

// ---------------- Threefry-2x32-20 (exact JAX partitionable semantics) ----------------
__device__ __forceinline__ uint32_t rotl32(uint32_t v, int d) { return (v << d) | (v >> (32 - d)); }

__device__ __forceinline__ void threefry2x32(uint32_t k0, uint32_t k1, uint32_t& x0, uint32_t& x1) {
  const uint32_t ks2 = k0 ^ k1 ^ 0x1BD11BDAu;
  x0 += k0; x1 += k1;
  x0 += x1; x1 = rotl32(x1, 13); x1 ^= x0;
  x0 += x1; x1 = rotl32(x1, 15); x1 ^= x0;
  x0 += x1; x1 = rotl32(x1, 26); x1 ^= x0;
  x0 += x1; x1 = rotl32(x1, 6);  x1 ^= x0;
  x0 += k1; x1 += ks2 + 1u;
  x0 += x1; x1 = rotl32(x1, 17); x1 ^= x0;
  x0 += x1; x1 = rotl32(x1, 29); x1 ^= x0;
  x0 += x1; x1 = rotl32(x1, 16); x1 ^= x0;
  x0 += x1; x1 = rotl32(x1, 24); x1 ^= x0;
  x0 += ks2; x1 += k0 + 2u;
  x0 += x1; x1 = rotl32(x1, 13); x1 ^= x0;
  x0 += x1; x1 = rotl32(x1, 15); x1 ^= x0;
  x0 += x1; x1 = rotl32(x1, 26); x1 ^= x0;
  x0 += x1; x1 = rotl32(x1, 6);  x1 ^= x0;
  x0 += k0; x1 += k1 + 3u;
  x0 += x1; x1 = rotl32(x1, 17); x1 ^= x0;
  x0 += x1; x1 = rotl32(x1, 29); x1 ^= x0;
  x0 += x1; x1 = rotl32(x1, 16); x1 ^= x0;
  x0 += x1; x1 = rotl32(x1, 24); x1 ^= x0;
  x0 += k1; x1 += ks2 + 4u;
  x0 += x1; x1 = rotl32(x1, 13); x1 ^= x0;
  x0 += x1; x1 = rotl32(x1, 15); x1 ^= x0;
  x0 += x1; x1 = rotl32(x1, 26); x1 ^= x0;
  x0 += x1; x1 = rotl32(x1, 6);  x1 ^= x0;
  x0 += ks2; x1 += k0 + 5u;
}

// ---------------- prep: cast z->bf16 | transpose+cast W1,WR | decode prog ----------------
__global__ __launch_bounds__(256) void prep_kernel(const float* __restrict__ z,
                                                   unsigned short* __restrict__ zb, int n8,
                                                   const float* __restrict__ W1,
                                                   const float* __restrict__ WR,
                                                   unsigned short* __restrict__ W1t,
                                                   unsigned short* __restrict__ WRt,
                                                   const float* __restrict__ P_op,
                                                   const float* __restrict__ P_dst,
                                                   const float* __restrict__ P_s1,
                                                   const float* __restrict__ P_s2,
                                                   const float* __restrict__ P_imm,
                                                   const float* __restrict__ Plen,
                                                   float* __restrict__ prog,
                                                   float* __restrict__ plen, int BT) {
  __shared__ float t[32][33];
  const int tid = threadIdx.x;
  const int bx = blockIdx.x;
  if (bx < 2048) {                       // ---- cast z -> bf16 ----
    const int i = bx * 256 + tid;
    if (i >= n8) return;
    const float4 a = reinterpret_cast<const float4*>(z)[i * 2];
    const float4 b = reinterpret_cast<const float4*>(z)[i * 2 + 1];
    ushort8 u;
    u[0] = f2bf(a.x); u[1] = f2bf(a.y); u[2] = f2bf(a.z); u[3] = f2bf(a.w);
    u[4] = f2bf(b.x); u[5] = f2bf(b.y); u[6] = f2bf(b.z); u[7] = f2bf(b.w);
    reinterpret_cast<ushort8*>(zb)[i] = u;
  } else if (bx < 2688) {                // ---- transpose + cast weights ----
    const int b = bx - 2048;
    const float* src; unsigned short* dst; int N, K, k0, n0;
    if (b < 512) {
      src = W1; dst = W1t; N = 1024; K = 512;
      k0 = (b & 15) * 32; n0 = (b >> 4) * 32;
    } else {
      const int b2 = b - 512;
      src = WR; dst = WRt; N = 128; K = 1024;
      k0 = (b2 & 31) * 32; n0 = (b2 >> 5) * 32;
    }
    {
      const int row = tid >> 3, c4 = (tid & 7) * 4;
      const float4 v = *reinterpret_cast<const float4*>(&src[(size_t)(k0 + row) * N + n0 + c4]);
      t[row][c4] = v.x; t[row][c4 + 1] = v.y; t[row][c4 + 2] = v.z; t[row][c4 + 3] = v.w;
    }
    __syncthreads();
    {
      const int n = tid >> 3, k4 = (tid & 7) * 4;
      ushort4v o;
      o.x = f2bf(t[k4 + 0][n]); o.y = f2bf(t[k4 + 1][n]);
      o.z = f2bf(t[k4 + 2][n]); o.w = f2bf(t[k4 + 3][n]);
      *reinterpret_cast<ushort4v*>(&dst[(size_t)(n0 + n) * K + k0 + k4]) = o;
    }
  } else {                               // ---- decode prog ----
    const int i = (bx - 2688) * 256 + tid;
    if (i >= BT) return;
    const float* po = P_op + (size_t)i * 4;
    const float op = po[0] + 2.f * po[1] + 4.f * po[2] + 8.f * po[3];
    const float* pd = P_dst + (size_t)i * 3;
    const float dv = pd[0] + 2.f * pd[1] + 4.f * pd[2];
    const float* p1 = P_s1 + (size_t)i * 3;
    const float s1v = p1[0] + 2.f * p1[1] + 4.f * p1[2];
    const float* p2 = P_s2 + (size_t)i * 3;
    const float s2v = p2[0] + 2.f * p2[1] + 4.f * p2[2];
    const float* pi = P_imm + (size_t)i * 3;
    const float imv = pi[0] + 2.f * pi[1] + 4.f * pi[2];
    float* o = prog + (size_t)i * 5;
    o[0] = op; o[1] = dv; o[2] = s1v; o[3] = s2v; o[4] = imv;
    if ((i & 15) == 0) {
      const int b = i >> 4;
      const float* pl = Plen + (size_t)b * 4;
      plen[b] = pl[0] + 2.f * pl[1] + 4.f * pl[2] + 8.f * pl[3];
    }
  }
}

// ---------------- fused GEMM1 + GEMM2-slice + threshold-slice, XCD-swizzled grid ----------------
// wgid -> (bx,by) such that XCD k (= wgid&7 under round-robin dispatch) owns by in [8k,8k+8) x all bx:
// zb row-strips become XCD-L2-resident (1 HBM fetch each) instead of being fetched by 8 XCDs.
__global__ __launch_bounds__(256) void gemm_fused(const unsigned short* __restrict__ zb,
                                                  const unsigned short* __restrict__ W1t,
                                                  const float* __restrict__ b1,
                                                  const unsigned short* __restrict__ WRt,
                                                  const float* __restrict__ Wt,
                                                  float* __restrict__ part,
                                                  float* __restrict__ thr_part, int B) {
  __shared__ __align__(16) char smem[34816];
  unsigned short* AsF = (unsigned short*)smem;            // phase 1: [128][64] swizzled
  unsigned short* BsF = (unsigned short*)(smem + 16384);  // phase 1: [128][64] swizzled
  auto H2 = reinterpret_cast<unsigned short (*)[136]>(smem);  // phase 2/3: [128][136]

  const int tid = threadIdx.x;
  const int lane = tid & 63, wave = tid >> 6;
  const int wm = wave >> 1, wn = wave & 1;
  const int wgid = blockIdx.x;                  // 0..511
  const int work = (wgid & 7) * 64 + (wgid >> 3);
  const int by = work >> 3, bx = work & 7;
  const int bm = by * 128, bn = bx * 128;

  f32x4 acc[4][4];
#pragma unroll
  for (int i = 0; i < 4; ++i)
#pragma unroll
    for (int j = 0; j < 4; ++j) acc[i][j] = (f32x4)0.f;

  const int fr = lane & 15, kc = (lane >> 4) * 8;
  const int lr = (lane >> 4) * 4, lc = lane & 15;
  const int lrow = lane >> 3, slot = lane & 7;
  const int sslot = (slot ^ lrow) << 3;
  const int fx = fr & 7;
  const int cbase = lane >> 4;

  // ---- phase 1: GEMM1 over K=512, BK=64, async staging ----
  for (int k0 = 0; k0 < 512; k0 += 64) {
#pragma unroll
    for (int i = 0; i < 4; ++i) {
      const int r0 = wave * 32 + i * 8;
      gl_lds16(&zb[(size_t)(bm + r0 + lrow) * 512 + k0 + sslot], &AsF[r0 * 64]);
    }
#pragma unroll
    for (int i = 0; i < 4; ++i) {
      const int r0 = wave * 32 + i * 8;
      gl_lds16(&W1t[(size_t)(bn + r0 + lrow) * 512 + k0 + sslot], &BsF[r0 * 64]);
    }
    __syncthreads();
#pragma unroll
    for (int s = 0; s < 2; ++s) {
      short8 af[4], bfv[4];
#pragma unroll
      for (int f = 0; f < 4; ++f) {
        const int row = wm * 64 + f * 16 + fr;
        const int c = s * 4 + cbase;
        af[f] = *reinterpret_cast<const short8*>(&AsF[row * 64 + ((c ^ fx) << 3)]);
      }
#pragma unroll
      for (int f = 0; f < 4; ++f) {
        const int row = wn * 64 + f * 16 + fr;
        const int c = s * 4 + cbase;
        bfv[f] = *reinterpret_cast<const short8*>(&BsF[row * 64 + ((c ^ fx) << 3)]);
      }
#pragma unroll
      for (int fm = 0; fm < 4; ++fm)
#pragma unroll
        for (int fn = 0; fn < 4; ++fn)
          acc[fm][fn] = __builtin_amdgcn_mfma_f32_16x16x32_bf16(af[fm], bfv[fn], acc[fm][fn], 0, 0, 0);
    }
    __syncthreads();
  }

  // ---- epilogue: h_tile = relu(acc + b1) bf16 -> LDS H2 ----
#pragma unroll
  for (int fn = 0; fn < 4; ++fn) {
    const int col_l = wn * 64 + fn * 16 + lc;
    const float bv = b1[bn + col_l];
#pragma unroll
    for (int fm = 0; fm < 4; ++fm) {
      const int row_l0 = wm * 64 + fm * 16 + lr;
#pragma unroll
      for (int r = 0; r < 4; ++r)
        H2[row_l0 + r][col_l] = f2bf(fmaxf(acc[fm][fn][r] + bv, 0.f));
    }
  }
  __syncthreads();

  // ---- phase 3: threshold partial ----
  {
    const int row = tid >> 1, half = tid & 1;
    const unsigned short* hp = &H2[row][half * 64];
    const float* wp = &Wt[bn + half * 64];
    float s = 0.f;
#pragma unroll
    for (int j = 0; j < 8; ++j) {
      const ushort8 a = *reinterpret_cast<const ushort8*>(hp + j * 8);
      const float4 w0 = *reinterpret_cast<const float4*>(wp + j * 8);
      const float4 w1 = *reinterpret_cast<const float4*>(wp + j * 8 + 4);
      s += bf2f(a[0]) * w0.x + bf2f(a[1]) * w0.y + bf2f(a[2]) * w0.z + bf2f(a[3]) * w0.w;
      s += bf2f(a[4]) * w1.x + bf2f(a[5]) * w1.y + bf2f(a[6]) * w1.z + bf2f(a[7]) * w1.w;
    }
    s += __shfl_xor(s, 1);
    if (half == 0) thr_part[(size_t)bx * B + bm + row] = s;
  }

  // ---- phase 2: GEMM2 slice ----
  f32x4 acc2[4][4];
#pragma unroll
  for (int i = 0; i < 4; ++i)
#pragma unroll
    for (int j = 0; j < 4; ++j) acc2[i][j] = (f32x4)0.f;

#pragma unroll
  for (int ks = 0; ks < 4; ++ks) {
    short8 af2[4], bf2v[4];
#pragma unroll
    for (int fm = 0; fm < 4; ++fm)
      af2[fm] = *reinterpret_cast<const short8*>(&H2[wm * 64 + fm * 16 + fr][ks * 32 + kc]);
#pragma unroll
    for (int fn = 0; fn < 4; ++fn)
      bf2v[fn] = *reinterpret_cast<const short8*>(
          &WRt[(size_t)(wn * 64 + fn * 16 + fr) * 1024 + bn + ks * 32 + kc]);
#pragma unroll
    for (int fm = 0; fm < 4; ++fm)
#pragma unroll
      for (int fn = 0; fn < 4; ++fn)
        acc2[fm][fn] = __builtin_amdgcn_mfma_f32_16x16x32_bf16(af2[fm], bf2v[fn], acc2[fm][fn], 0, 0, 0);
  }

  float* pp = part + (size_t)bx * B * 128;
#pragma unroll
  for (int fn = 0; fn < 4; ++fn) {
    const int col = wn * 64 + fn * 16 + lc;
#pragma unroll
    for (int fm = 0; fm < 4; ++fm) {
      const int row0 = bm + wm * 64 + fm * 16 + lr;
#pragma unroll
      for (int r = 0; r < 4; ++r)
        pp[(size_t)(row0 + r) * 128 + col] = acc2[fm][fn][r];
    }
  }
}

// ---------------- fused partial-reduce + sigmoid + soft-VM scan + threshold finish ----------------
__global__ __launch_bounds__(256) void scan2_kernel(const float* __restrict__ part,
                                                    const float* __restrict__ bR,
                                                    const float* __restrict__ thr_part,
                                                    const float* __restrict__ bt,
                                                    const float* __restrict__ prog,
                                                    const float* __restrict__ plen,
                                                    float* __restrict__ Rfinal,
                                                    float* __restrict__ thr_out, int B) {
  __shared__ float s_bits[16][128];
  __shared__ float s_prog[16][80];
  __shared__ float s_plen[16];
  const int tid = threadIdx.x;
  const int b0 = blockIdx.x * 16;
#pragma unroll
  for (int j = 0; j < 8; ++j) {
    const int f = tid + 256 * j;   // 0..2047
    const int lb = f >> 7, c = f & 127;
    float s = part[(size_t)(b0 + lb) * 128 + c];
#pragma unroll
    for (int sl = 1; sl < 8; ++sl)
      s += part[(size_t)sl * B * 128 + (size_t)(b0 + lb) * 128 + c];
    s_bits[lb][c] = 1.f / (1.f + expf(-(s + bR[c])));
  }
#pragma unroll
  for (int j = 0; j < 5; ++j) {
    const int f = tid + 256 * j;
    s_prog[f / 80][f % 80] = prog[(size_t)b0 * 80 + f];
  }
  if (tid < 16) {
    s_plen[tid] = plen[b0 + tid];
    float s = thr_part[b0 + tid];
#pragma unroll
    for (int sl = 1; sl < 8; ++sl) s += thr_part[(size_t)sl * B + b0 + tid];
    thr_out[b0 + tid] = 1.f / (1.f + expf(-(s + bt[0])));
  }
  __syncthreads();

  const int lb = tid >> 4, g = tid & 15;
  const int bg = (b0 + lb) * 16 + g;

  uint32_t k2a, k2b;
  { uint32_t x0 = 0u, x1 = 1u; threefry2x32(0u, 42u, x0, x1); k2a = x0; k2b = x1; }
  uint32_t p0, p1;
  {
    uint32_t x0 = 0u, x1 = (uint32_t)bg * 2u;
    threefry2x32(k2a, k2b, x0, x1);
    p0 = (x0 ^ x1) & 127u;
  }
  {
    uint32_t x0 = 0u, x1 = (uint32_t)bg * 2u + 1u;
    threefry2x32(k2a, k2b, x0, x1);
    p1 = (x0 ^ x1) & 127u;
  }

  float R[8], M[8];
#pragma unroll
  for (int r = 0; r < 8; ++r) {
    float a = 0.f;
#pragma unroll
    for (int bit = 0; bit < 16; ++bit) {
      const int pos = r * 16 + bit;
      float v = s_bits[lb][pos];
      const bool flip = (g != 0) && ((int)p0 == pos || (int)p1 == pos);
      v = flip ? 1.0f - v : v;
      a = fmaf(v, (float)(1 << bit), a);
    }
    R[r] = a;
    M[r] = 0.f;
  }

  const float pl = s_plen[lb];
  for (int t = 0; t < 16; ++t) {
    const float op = s_prog[lb][t * 5 + 0];
    const float dst = s_prog[lb][t * 5 + 1];
    const float sa = s_prog[lb][t * 5 + 2];
    const float sb = s_prog[lb][t * 5 + 3];
    const float imm = s_prog[lb][t * 5 + 4];
    const float active = fminf(fmaxf(pl - (float)t, 0.f), 1.f);
    float r1 = 0.f, r2 = 0.f, m1 = 0.f, old = 0.f;
    float wd[8];
#pragma unroll
    for (int i = 0; i < 8; ++i) {
      const float w1 = fmaxf(1.f - fabsf(sa - (float)i), 0.f);
      const float w2 = fmaxf(1.f - fabsf(sb - (float)i), 0.f);
      wd[i] = fmaxf(1.f - fabsf(dst - (float)i), 0.f);
      r1 = fmaf(w1, R[i], r1);
      r2 = fmaf(w2, R[i], r2);
      m1 = fmaf(w1, M[i], m1);
      old = fmaf(wd[i], R[i], old);
    }
    float results[16];
    results[0] = old;               results[1] = r1 + r2;
    results[2] = r1 - r2;           results[3] = r1 * r2 * (1.f / 65536.f);
    results[4] = r1;                results[5] = imm;
    results[6] = r1 + imm;          results[7] = fmaxf(r1, r2);
    results[8] = fminf(r1, r2);     results[9] = -r1;
    results[10] = 0.5f * r1;        results[11] = r2;
    results[12] = m1;               results[13] = old;
    results[14] = fabsf(r1);        results[15] = old;
    float res = 0.f;
    const float pstore = fmaxf(1.f - fabsf(op - 13.f), 0.f);
#pragma unroll
    for (int o = 0; o < 16; ++o) res = fmaf(fmaxf(1.f - fabsf(op - (float)o), 0.f), results[o], res);
#pragma unroll
    for (int i = 0; i < 8; ++i) {
      R[i] = fmaf(active * wd[i], res - R[i], R[i]);
      M[i] = fmaf(active * pstore * wd[i], r1 - M[i], M[i]);
    }
  }

  float* outp = Rfinal + (size_t)bg * 8;
#pragma unroll
  for (int r = 0; r < 8; ++r) outp[r] = R[r];
}

// ---------------- expand: W fragment in registers, each wave loops 32 rows ----------------
__global__ __launch_bounds__(256) void final_expand2(const float* __restrict__ Rf,
                                                     const float* __restrict__ W,
                                                     const float* __restrict__ bias,
                                                     const float* __restrict__ gam,
                                                     const float* __restrict__ bet,
                                                     float* __restrict__ out, int rowsPerWave) {
  const int lane = threadIdx.x & 63;
  const int w = blockIdx.x * 4 + (threadIdx.x >> 6);
  const int h0 = lane * 8;

  float wreg[8][8];
#pragma unroll
  for (int reg = 0; reg < 8; ++reg) {
    const float4 wa = *reinterpret_cast<const float4*>(&W[reg * 512 + h0]);
    const float4 wb = *reinterpret_cast<const float4*>(&W[reg * 512 + h0 + 4]);
    wreg[reg][0] = wa.x; wreg[reg][1] = wa.y; wreg[reg][2] = wa.z; wreg[reg][3] = wa.w;
    wreg[reg][4] = wb.x; wreg[reg][5] = wb.y; wreg[reg][6] = wb.z; wreg[reg][7] = wb.w;
  }
  float bi[8], ga[8], be[8];
  {
    const float4 a = *reinterpret_cast<const float4*>(&bias[h0]);
    const float4 b = *reinterpret_cast<const float4*>(&bias[h0 + 4]);
    bi[0] = a.x; bi[1] = a.y; bi[2] = a.z; bi[3] = a.w; bi[4] = b.x; bi[5] = b.y; bi[6] = b.z; bi[7] = b.w;
    const float4 c = *reinterpret_cast<const float4*>(&gam[h0]);
    const float4 d = *reinterpret_cast<const float4*>(&gam[h0 + 4]);
    ga[0] = c.x; ga[1] = c.y; ga[2] = c.z; ga[3] = c.w; ga[4] = d.x; ga[5] = d.y; ga[6] = d.z; ga[7] = d.w;
    const float4 e = *reinterpret_cast<const float4*>(&bet[h0]);
    const float4 f = *reinterpret_cast<const float4*>(&bet[h0 + 4]);
    be[0] = e.x; be[1] = e.y; be[2] = e.z; be[3] = e.w; be[4] = f.x; be[5] = f.y; be[6] = f.z; be[7] = f.w;
  }

  const int r0 = w * rowsPerWave;
  for (int i = 0; i < rowsPerWave; ++i) {
    const int row = r0 + i;
    const float4 ra = *reinterpret_cast<const float4*>(&Rf[(size_t)row * 8]);
    const float4 rb = *reinterpret_cast<const float4*>(&Rf[(size_t)row * 8 + 4]);
    const float r[8] = {ra.x, ra.y, ra.z, ra.w, rb.x, rb.y, rb.z, rb.w};
    float x[8];
#pragma unroll
    for (int j = 0; j < 8; ++j) x[j] = bi[j];
#pragma unroll
    for (int reg = 0; reg < 8; ++reg)
#pragma unroll
      for (int j = 0; j < 8; ++j) x[j] = fmaf(r[reg], wreg[reg][j], x[j]);
    float s1 = 0.f, s2 = 0.f;
#pragma unroll
    for (int j = 0; j < 8; ++j) { s1 += x[j]; s2 = fmaf(x[j], x[j], s2); }
#pragma unroll
    for (int off = 32; off; off >>= 1) { s1 += __shfl_xor(s1, off); s2 += __shfl_xor(s2, off); }
    const float mean = s1 * (1.f / 512.f);
    const float var = s2 * (1.f / 512.f) - mean * mean;
    const float inv = rsqrtf(var + 1e-5f);
    float y[8];
#pragma unroll
    for (int j = 0; j < 8; ++j) y[j] = (x[j] - mean) * inv * ga[j] + be[j];
    float* dst = out + (size_t)row * 512 + h0;
    *reinterpret_cast<float4*>(dst) = make_float4(y[0], y[1], y[2], y[3]);
    *reinterpret_cast<float4*>(dst + 4) = make_float4(y[4], y[5], y[6], y[7]);
  }
}

// ---------------- launch ----------------
extern "C" void kernel_launch(void* const* d_in, const int* in_sizes, int n_in,
                              void* d_out, int out_size, void* d_ws, size_t ws_size,
                              hipStream_t stream) {
  const float* z    = (const float*)d_in[0];
  const float* P_op = (const float*)d_in[1];
  const float* P_dst= (const float*)d_in[2];
  const float* P_s1 = (const float*)d_in[3];
  const float* P_s2 = (const float*)d_in[4];
  const float* P_imm= (const float*)d_in[5];
  const float* Plen = (const float*)d_in[6];
  const float* W1   = (const float*)d_in[8];
  const float* b1   = (const float*)d_in[9];
  const float* WR   = (const float*)d_in[10];
  const float* bR   = (const float*)d_in[11];
  const float* Wt   = (const float*)d_in[12];
  const float* bt   = (const float*)d_in[13];
  const float* W_r2h= (const float*)d_in[14];
  const float* b_r2h= (const float*)d_in[15];
  const float* ln_g = (const float*)d_in[16];
  const float* ln_b = (const float*)d_in[17];

  const int B = in_sizes[0] / 512;  // 8192
  float* out = (float*)d_out;
  float* part    = out + (size_t)(1 << 25);            // 8 * B*128 f32 K-split partials (read before expand writes)
  float* thr_out = out + (size_t)B * 16 * 512;         // threshold output region

  float* ws = (float*)d_ws;
  float* prog   = ws;                                  // B*16*5
  float* plen   = prog + (size_t)B * 80;               // B
  float* Rfinal = plen + B;                            // B*16*8
  float* thr_part = Rfinal + (size_t)B * 128;          // 8 * B
  unsigned short* W1t = (unsigned short*)(thr_part + (size_t)8 * B);  // 1024x512 bf16
  unsigned short* WRt = W1t + (size_t)1024 * 512;                     // 128x1024 bf16
  unsigned short* zb  = WRt + (size_t)128 * 1024;                     // B*512 bf16

  const dim3 blk(256);
  prep_kernel<<<dim3(3200), blk, 0, stream>>>(z, zb, B * 512 / 8, W1, WR, W1t, WRt,
                                              P_op, P_dst, P_s1, P_s2, P_imm, Plen,
                                              prog, plen, B * 16);
  gemm_fused<<<dim3(512), blk, 0, stream>>>(zb, W1t, b1, WRt, Wt, part, thr_part, B);
  scan2_kernel<<<dim3(B / 16), blk, 0, stream>>>(part, bR, thr_part, bt, prog, plen, Rfinal,
                                                 thr_out, B);
  final_expand2<<<dim3(B * 16 / 4 / 32), blk, 0, stream>>>(Rfinal, W_r2h, b_r2h, ln_g, ln_b, out,
                                                           32);
}

// Round 12
// 111.222 us; speedup vs baseline: 1.0518x; 1.0065x over previous
//
#include <hip/hip_runtime.h>
#include <stdint.h>

typedef __attribute__((ext_vector_type(8))) short short8;
typedef __attribute__((ext_vector_type(4))) float f32x4;
typedef __attribute__((ext_vector_type(8))) unsigned short ushort8;
typedef __attribute__((ext_vector_type(4))) unsigned short ushort4v;

__device__ __forceinline__ unsigned short f2bf(float f) {
  uint32_t u = __float_as_uint(f);
  uint32_t r = (u + 0x7fffu + ((u >> 16) & 1u)) >> 16;  // RNE
  return (unsigned short)r;
}
__device__ __forceinline__ float bf2f(unsigned short v) {
  return __uint_as_float(((uint32_t)v) << 16);
}

typedef __attribute__((address_space(1))) const unsigned int g_u32;
typedef __attribute__((address_space(3))) unsigned int l_u32;
__device__ __forceinline__ void gl_lds16(const void* g, void* l) {
  __builtin_amdgcn_global_load_lds((g_u32*)g, (l_u32*)l, 16, 0, 0);
}

// ---------------- Threefry-2x32-20 (exact JAX partitionable semantics) ----------------
__device__ __forceinline__ uint32_t rotl32(uint32_t v, int d) { return (v << d) | (v >> (32 - d)); }

__device__ __forceinline__ void threefry2x32(uint32_t k0, uint32_t k1, uint32_t& x0, uint32_t& x1) {
  const uint32_t ks2 = k0 ^ k1 ^ 0x1BD11BDAu;
  x0 += k0; x1 += k1;
  x0 += x1; x1 = rotl32(x1, 13); x1 ^= x0;
  x0 += x1; x1 = rotl32(x1, 15); x1 ^= x0;
  x0 += x1; x1 = rotl32(x1, 26); x1 ^= x0;
  x0 += x1; x1 = rotl32(x1, 6);  x1 ^= x0;
  x0 += k1; x1 += ks2 + 1u;
  x0 += x1; x1 = rotl32(x1, 17); x1 ^= x0;
  x0 += x1; x1 = rotl32(x1, 29); x1 ^= x0;
  x0 += x1; x1 = rotl32(x1, 16); x1 ^= x0;
  x0 += x1; x1 = rotl32(x1, 24); x1 ^= x0;
  x0 += ks2; x1 += k0 + 2u;
  x0 += x1; x1 = rotl32(x1, 13); x1 ^= x0;
  x0 += x1; x1 = rotl32(x1, 15); x1 ^= x0;
  x0 += x1; x1 = rotl32(x1, 26); x1 ^= x0;
  x0 += x1; x1 = rotl32(x1, 6);  x1 ^= x0;
  x0 += k0; x1 += k1 + 3u;
  x0 += x1; x1 = rotl32(x1, 17); x1 ^= x0;
  x0 += x1; x1 = rotl32(x1, 29); x1 ^= x0;
  x0 += x1; x1 = rotl32(x1, 16); x1 ^= x0;
  x0 += x1; x1 = rotl32(x1, 24); x1 ^= x0;
  x0 += k1; x1 += ks2 + 4u;
  x0 += x1; x1 = rotl32(x1, 13); x1 ^= x0;
  x0 += x1; x1 = rotl32(x1, 15); x1 ^= x0;
  x0 += x1; x1 = rotl32(x1, 26); x1 ^= x0;
  x0 += x1; x1 = rotl32(x1, 6);  x1 ^= x0;
  x0 += ks2; x1 += k0 + 5u;
}

// ---------------- prep: cast z->bf16 | transpose+cast W1,WR | decode prog ----------------
__global__ __launch_bounds__(256) void prep_kernel(const float* __restrict__ z,
                                                   unsigned short* __restrict__ zb, int n8,
                                                   const float* __restrict__ W1,
                                                   const float* __restrict__ WR,
                                                   unsigned short* __restrict__ W1t,
                                                   unsigned short* __restrict__ WRt,
                                                   const float* __restrict__ P_op,
                                                   const float* __restrict__ P_dst,
                                                   const float* __restrict__ P_s1,
                                                   const float* __restrict__ P_s2,
                                                   const float* __restrict__ P_imm,
                                                   const float* __restrict__ Plen,
                                                   float* __restrict__ prog,
                                                   float* __restrict__ plen, int BT) {
  __shared__ float t[32][33];
  const int tid = threadIdx.x;
  const int bx = blockIdx.x;
  if (bx < 2048) {                       // ---- cast z -> bf16 ----
    const int i = bx * 256 + tid;
    if (i >= n8) return;
    const float4 a = reinterpret_cast<const float4*>(z)[i * 2];
    const float4 b = reinterpret_cast<const float4*>(z)[i * 2 + 1];
    ushort8 u;
    u[0] = f2bf(a.x); u[1] = f2bf(a.y); u[2] = f2bf(a.z); u[3] = f2bf(a.w);
    u[4] = f2bf(b.x); u[5] = f2bf(b.y); u[6] = f2bf(b.z); u[7] = f2bf(b.w);
    reinterpret_cast<ushort8*>(zb)[i] = u;
  } else if (bx < 2688) {                // ---- transpose + cast weights ----
    const int b = bx - 2048;
    const float* src; unsigned short* dst; int N, K, k0, n0;
    if (b < 512) {
      src = W1; dst = W1t; N = 1024; K = 512;
      k0 = (b & 15) * 32; n0 = (b >> 4) * 32;
    } else {
      const int b2 = b - 512;
      src = WR; dst = WRt; N = 128; K = 1024;
      k0 = (b2 & 31) * 32; n0 = (b2 >> 5) * 32;
    }
    {
      const int row = tid >> 3, c4 = (tid & 7) * 4;
      const float4 v = *reinterpret_cast<const float4*>(&src[(size_t)(k0 + row) * N + n0 + c4]);
      t[row][c4] = v.x; t[row][c4 + 1] = v.y; t[row][c4 + 2] = v.z; t[row][c4 + 3] = v.w;
    }
    __syncthreads();
    {
      const int n = tid >> 3, k4 = (tid & 7) * 4;
      ushort4v o;
      o.x = f2bf(t[k4 + 0][n]); o.y = f2bf(t[k4 + 1][n]);
      o.z = f2bf(t[k4 + 2][n]); o.w = f2bf(t[k4 + 3][n]);
      *reinterpret_cast<ushort4v*>(&dst[(size_t)(n0 + n) * K + k0 + k4]) = o;
    }
  } else {                               // ---- decode prog ----
    const int i = (bx - 2688) * 256 + tid;
    if (i >= BT) return;
    const float* po = P_op + (size_t)i * 4;
    const float op = po[0] + 2.f * po[1] + 4.f * po[2] + 8.f * po[3];
    const float* pd = P_dst + (size_t)i * 3;
    const float dv = pd[0] + 2.f * pd[1] + 4.f * pd[2];
    const float* p1 = P_s1 + (size_t)i * 3;
    const float s1v = p1[0] + 2.f * p1[1] + 4.f * p1[2];
    const float* p2 = P_s2 + (size_t)i * 3;
    const float s2v = p2[0] + 2.f * p2[1] + 4.f * p2[2];
    const float* pi = P_imm + (size_t)i * 3;
    const float imv = pi[0] + 2.f * pi[1] + 4.f * pi[2];
    float* o = prog + (size_t)i * 5;
    o[0] = op; o[1] = dv; o[2] = s1v; o[3] = s2v; o[4] = imv;
    if ((i & 15) == 0) {
      const int b = i >> 4;
      const float* pl = Plen + (size_t)b * 4;
      plen[b] = pl[0] + 2.f * pl[1] + 4.f * pl[2] + 8.f * pl[3];
    }
  }
}

// ---------------- fused GEMM1 + GEMM2-slice + threshold-slice, XCD-swizzled grid ----------------
__global__ __launch_bounds__(256) void gemm_fused(const unsigned short* __restrict__ zb,
                                                  const unsigned short* __restrict__ W1t,
                                                  const float* __restrict__ b1,
                                                  const unsigned short* __restrict__ WRt,
                                                  const float* __restrict__ Wt,
                                                  float* __restrict__ part,
                                                  float* __restrict__ thr_part, int B) {
  __shared__ __align__(16) char smem[34816];
  unsigned short* AsF = (unsigned short*)smem;            // phase 1: [128][64] swizzled
  unsigned short* BsF = (unsigned short*)(smem + 16384);  // phase 1: [128][64] swizzled
  auto H2 = reinterpret_cast<unsigned short (*)[136]>(smem);  // phase 2/3: [128][136]

  const int tid = threadIdx.x;
  const int lane = tid & 63, wave = tid >> 6;
  const int wm = wave >> 1, wn = wave & 1;
  const int wgid = blockIdx.x;                  // 0..511
  const int work = (wgid & 7) * 64 + (wgid >> 3);
  const int by = work >> 3, bx = work & 7;
  const int bm = by * 128, bn = bx * 128;

  f32x4 acc[4][4];
#pragma unroll
  for (int i = 0; i < 4; ++i)
#pragma unroll
    for (int j = 0; j < 4; ++j) acc[i][j] = (f32x4)0.f;

  const int fr = lane & 15, kc = (lane >> 4) * 8;
  const int lr = (lane >> 4) * 4, lc = lane & 15;
  const int lrow = lane >> 3, slot = lane & 7;
  const int sslot = (slot ^ lrow) << 3;
  const int fx = fr & 7;
  const int cbase = lane >> 4;

  // ---- phase 1: GEMM1 over K=512, BK=64, async staging ----
  for (int k0 = 0; k0 < 512; k0 += 64) {
#pragma unroll
    for (int i = 0; i < 4; ++i) {
      const int r0 = wave * 32 + i * 8;
      gl_lds16(&zb[(size_t)(bm + r0 + lrow) * 512 + k0 + sslot], &AsF[r0 * 64]);
    }
#pragma unroll
    for (int i = 0; i < 4; ++i) {
      const int r0 = wave * 32 + i * 8;
      gl_lds16(&W1t[(size_t)(bn + r0 + lrow) * 512 + k0 + sslot], &BsF[r0 * 64]);
    }
    __syncthreads();
#pragma unroll
    for (int s = 0; s < 2; ++s) {
      short8 af[4], bfv[4];
#pragma unroll
      for (int f = 0; f < 4; ++f) {
        const int row = wm * 64 + f * 16 + fr;
        const int c = s * 4 + cbase;
        af[f] = *reinterpret_cast<const short8*>(&AsF[row * 64 + ((c ^ fx) << 3)]);
      }
#pragma unroll
      for (int f = 0; f < 4; ++f) {
        const int row = wn * 64 + f * 16 + fr;
        const int c = s * 4 + cbase;
        bfv[f] = *reinterpret_cast<const short8*>(&BsF[row * 64 + ((c ^ fx) << 3)]);
      }
#pragma unroll
      for (int fm = 0; fm < 4; ++fm)
#pragma unroll
        for (int fn = 0; fn < 4; ++fn)
          acc[fm][fn] = __builtin_amdgcn_mfma_f32_16x16x32_bf16(af[fm], bfv[fn], acc[fm][fn], 0, 0, 0);
    }
    __syncthreads();
  }

  // ---- epilogue: h_tile = relu(acc + b1) bf16 -> LDS H2 ----
#pragma unroll
  for (int fn = 0; fn < 4; ++fn) {
    const int col_l = wn * 64 + fn * 16 + lc;
    const float bv = b1[bn + col_l];
#pragma unroll
    for (int fm = 0; fm < 4; ++fm) {
      const int row_l0 = wm * 64 + fm * 16 + lr;
#pragma unroll
      for (int r = 0; r < 4; ++r)
        H2[row_l0 + r][col_l] = f2bf(fmaxf(acc[fm][fn][r] + bv, 0.f));
    }
  }
  __syncthreads();

  // ---- phase 3: threshold partial ----
  {
    const int row = tid >> 1, half = tid & 1;
    const unsigned short* hp = &H2[row][half * 64];
    const float* wp = &Wt[bn + half * 64];
    float s = 0.f;
#pragma unroll
    for (int j = 0; j < 8; ++j) {
      const ushort8 a = *reinterpret_cast<const ushort8*>(hp + j * 8);
      const float4 w0 = *reinterpret_cast<const float4*>(wp + j * 8);
      const float4 w1 = *reinterpret_cast<const float4*>(wp + j * 8 + 4);
      s += bf2f(a[0]) * w0.x + bf2f(a[1]) * w0.y + bf2f(a[2]) * w0.z + bf2f(a[3]) * w0.w;
      s += bf2f(a[4]) * w1.x + bf2f(a[5]) * w1.y + bf2f(a[6]) * w1.z + bf2f(a[7]) * w1.w;
    }
    s += __shfl_xor(s, 1);
    if (half == 0) thr_part[(size_t)bx * B + bm + row] = s;
  }

  // ---- phase 2: GEMM2 slice ----
  f32x4 acc2[4][4];
#pragma unroll
  for (int i = 0; i < 4; ++i)
#pragma unroll
    for (int j = 0; j < 4; ++j) acc2[i][j] = (f32x4)0.f;

#pragma unroll
  for (int ks = 0; ks < 4; ++ks) {
    short8 af2[4], bf2v[4];
#pragma unroll
    for (int fm = 0; fm < 4; ++fm)
      af2[fm] = *reinterpret_cast<const short8*>(&H2[wm * 64 + fm * 16 + fr][ks * 32 + kc]);
#pragma unroll
    for (int fn = 0; fn < 4; ++fn)
      bf2v[fn] = *reinterpret_cast<const short8*>(
          &WRt[(size_t)(wn * 64 + fn * 16 + fr) * 1024 + bn + ks * 32 + kc]);
#pragma unroll
    for (int fm = 0; fm < 4; ++fm)
#pragma unroll
      for (int fn = 0; fn < 4; ++fn)
        acc2[fm][fn] = __builtin_amdgcn_mfma_f32_16x16x32_bf16(af2[fm], bf2v[fn], acc2[fm][fn], 0, 0, 0);
  }

  float* pp = part + (size_t)bx * B * 128;
#pragma unroll
  for (int fn = 0; fn < 4; ++fn) {
    const int col = wn * 64 + fn * 16 + lc;
#pragma unroll
    for (int fm = 0; fm < 4; ++fm) {
      const int row0 = bm + wm * 64 + fm * 16 + lr;
#pragma unroll
      for (int r = 0; r < 4; ++r)
        pp[(size_t)(row0 + r) * 128 + col] = acc2[fm][fn][r];
    }
  }
}

// ---------------- fused partial-reduce + sigmoid + soft-VM scan + threshold finish ----------------
__global__ __launch_bounds__(256) void scan2_kernel(const float* __restrict__ part,
                                                    const float* __restrict__ bR,
                                                    const float* __restrict__ thr_part,
                                                    const float* __restrict__ bt,
                                                    const float* __restrict__ prog,
                                                    const float* __restrict__ plen,
                                                    float* __restrict__ Rfinal,
                                                    float* __restrict__ thr_out, int B) {
  __shared__ float s_bits[16][128];
  __shared__ float s_prog[16][80];
  __shared__ float s_plen[16];
  const int tid = threadIdx.x;
  const int b0 = blockIdx.x * 16;
#pragma unroll
  for (int j = 0; j < 8; ++j) {
    const int f = tid + 256 * j;   // 0..2047
    const int lb = f >> 7, c = f & 127;
    float s = part[(size_t)(b0 + lb) * 128 + c];
#pragma unroll
    for (int sl = 1; sl < 8; ++sl)
      s += part[(size_t)sl * B * 128 + (size_t)(b0 + lb) * 128 + c];
    s_bits[lb][c] = 1.f / (1.f + expf(-(s + bR[c])));
  }
#pragma unroll
  for (int j = 0; j < 5; ++j) {
    const int f = tid + 256 * j;
    s_prog[f / 80][f % 80] = prog[(size_t)b0 * 80 + f];
  }
  if (tid < 16) {
    s_plen[tid] = plen[b0 + tid];
    float s = thr_part[b0 + tid];
#pragma unroll
    for (int sl = 1; sl < 8; ++sl) s += thr_part[(size_t)sl * B + b0 + tid];
    thr_out[b0 + tid] = 1.f / (1.f + expf(-(s + bt[0])));
  }
  __syncthreads();

  const int lb = tid >> 4, g = tid & 15;
  const int bg = (b0 + lb) * 16 + g;

  uint32_t k2a, k2b;
  { uint32_t x0 = 0u, x1 = 1u; threefry2x32(0u, 42u, x0, x1); k2a = x0; k2b = x1; }
  uint32_t p0, p1;
  {
    uint32_t x0 = 0u, x1 = (uint32_t)bg * 2u;
    threefry2x32(k2a, k2b, x0, x1);
    p0 = (x0 ^ x1) & 127u;
  }
  {
    uint32_t x0 = 0u, x1 = (uint32_t)bg * 2u + 1u;
    threefry2x32(k2a, k2b, x0, x1);
    p1 = (x0 ^ x1) & 127u;
  }

  float R[8], M[8];
#pragma unroll
  for (int r = 0; r < 8; ++r) {
    float a = 0.f;
#pragma unroll
    for (int bit = 0; bit < 16; ++bit) {
      const int pos = r * 16 + bit;
      float v = s_bits[lb][pos];
      const bool flip = (g != 0) && ((int)p0 == pos || (int)p1 == pos);
      v = flip ? 1.0f - v : v;
      a = fmaf(v, (float)(1 << bit), a);
    }
    R[r] = a;
    M[r] = 0.f;
  }

  const float pl = s_plen[lb];
  for (int t = 0; t < 16; ++t) {
    const float op = s_prog[lb][t * 5 + 0];
    const float dst = s_prog[lb][t * 5 + 1];
    const float sa = s_prog[lb][t * 5 + 2];
    const float sb = s_prog[lb][t * 5 + 3];
    const float imm = s_prog[lb][t * 5 + 4];
    const float active = fminf(fmaxf(pl - (float)t, 0.f), 1.f);
    float r1 = 0.f, r2 = 0.f, m1 = 0.f, old = 0.f;
    float wd[8];
#pragma unroll
    for (int i = 0; i < 8; ++i) {
      const float w1 = fmaxf(1.f - fabsf(sa - (float)i), 0.f);
      const float w2 = fmaxf(1.f - fabsf(sb - (float)i), 0.f);
      wd[i] = fmaxf(1.f - fabsf(dst - (float)i), 0.f);
      r1 = fmaf(w1, R[i], r1);
      r2 = fmaf(w2, R[i], r2);
      m1 = fmaf(w1, M[i], m1);
      old = fmaf(wd[i], R[i], old);
    }
    float results[16];
    results[0] = old;               results[1] = r1 + r2;
    results[2] = r1 - r2;           results[3] = r1 * r2 * (1.f / 65536.f);
    results[4] = r1;                results[5] = imm;
    results[6] = r1 + imm;          results[7] = fmaxf(r1, r2);
    results[8] = fminf(r1, r2);     results[9] = -r1;
    results[10] = 0.5f * r1;        results[11] = r2;
    results[12] = m1;               results[13] = old;
    results[14] = fabsf(r1);        results[15] = old;
    float res = 0.f;
    const float pstore = fmaxf(1.f - fabsf(op - 13.f), 0.f);
#pragma unroll
    for (int o = 0; o < 16; ++o) res = fmaf(fmaxf(1.f - fabsf(op - (float)o), 0.f), results[o], res);
#pragma unroll
    for (int i = 0; i < 8; ++i) {
      R[i] = fmaf(active * wd[i], res - R[i], R[i]);
      M[i] = fmaf(active * pstore * wd[i], r1 - M[i], M[i]);
    }
  }

  float* outp = Rfinal + (size_t)bg * 8;
  *reinterpret_cast<float4*>(outp) = make_float4(R[0], R[1], R[2], R[3]);
  *reinterpret_cast<float4*>(outp + 4) = make_float4(R[4], R[5], R[6], R[7]);
}

// ---------------- expand: coalesced column partition — lane i owns cols [4i,4i+4) and [256+4i,+4) ----
// Each float4 store instruction is a fully-contiguous 1KB line-aligned wave write (no half-line masks).
__global__ __launch_bounds__(256) void final_expand2(const float* __restrict__ Rf,
                                                     const float* __restrict__ W,
                                                     const float* __restrict__ bias,
                                                     const float* __restrict__ gam,
                                                     const float* __restrict__ bet,
                                                     float* __restrict__ out, int rowsPerWave) {
  const int lane = threadIdx.x & 63;
  const int w = blockIdx.x * 4 + (threadIdx.x >> 6);
  const int cA = lane * 4, cB = 256 + lane * 4;   // two contiguous 4-col slices per lane

  float wreg[8][8];   // [reg][j]: j<4 -> col cA+j, j>=4 -> col cB+(j-4)
#pragma unroll
  for (int reg = 0; reg < 8; ++reg) {
    const float4 wa = *reinterpret_cast<const float4*>(&W[reg * 512 + cA]);
    const float4 wb = *reinterpret_cast<const float4*>(&W[reg * 512 + cB]);
    wreg[reg][0] = wa.x; wreg[reg][1] = wa.y; wreg[reg][2] = wa.z; wreg[reg][3] = wa.w;
    wreg[reg][4] = wb.x; wreg[reg][5] = wb.y; wreg[reg][6] = wb.z; wreg[reg][7] = wb.w;
  }
  float bi[8], ga[8], be[8];
  {
    const float4 a = *reinterpret_cast<const float4*>(&bias[cA]);
    const float4 b = *reinterpret_cast<const float4*>(&bias[cB]);
    bi[0] = a.x; bi[1] = a.y; bi[2] = a.z; bi[3] = a.w; bi[4] = b.x; bi[5] = b.y; bi[6] = b.z; bi[7] = b.w;
    const float4 c = *reinterpret_cast<const float4*>(&gam[cA]);
    const float4 d = *reinterpret_cast<const float4*>(&gam[cB]);
    ga[0] = c.x; ga[1] = c.y; ga[2] = c.z; ga[3] = c.w; ga[4] = d.x; ga[5] = d.y; ga[6] = d.z; ga[7] = d.w;
    const float4 e = *reinterpret_cast<const float4*>(&bet[cA]);
    const float4 f = *reinterpret_cast<const float4*>(&bet[cB]);
    be[0] = e.x; be[1] = e.y; be[2] = e.z; be[3] = e.w; be[4] = f.x; be[5] = f.y; be[6] = f.z; be[7] = f.w;
  }

  const int r0 = w * rowsPerWave;
  for (int i = 0; i < rowsPerWave; ++i) {
    const int row = r0 + i;
    const float4 ra = *reinterpret_cast<const float4*>(&Rf[(size_t)row * 8]);
    const float4 rb = *reinterpret_cast<const float4*>(&Rf[(size_t)row * 8 + 4]);
    const float r[8] = {ra.x, ra.y, ra.z, ra.w, rb.x, rb.y, rb.z, rb.w};
    float x[8];
#pragma unroll
    for (int j = 0; j < 8; ++j) x[j] = bi[j];
#pragma unroll
    for (int reg = 0; reg < 8; ++reg)
#pragma unroll
      for (int j = 0; j < 8; ++j) x[j] = fmaf(r[reg], wreg[reg][j], x[j]);
    float s1 = 0.f, s2 = 0.f;
#pragma unroll
    for (int j = 0; j < 8; ++j) { s1 += x[j]; s2 = fmaf(x[j], x[j], s2); }
#pragma unroll
    for (int off = 32; off; off >>= 1) { s1 += __shfl_xor(s1, off); s2 += __shfl_xor(s2, off); }
    const float mean = s1 * (1.f / 512.f);
    const float var = s2 * (1.f / 512.f) - mean * mean;
    const float inv = rsqrtf(var + 1e-5f);
    float y[8];
#pragma unroll
    for (int j = 0; j < 8; ++j) y[j] = (x[j] - mean) * inv * ga[j] + be[j];
    float* dst = out + (size_t)row * 512;
    *reinterpret_cast<float4*>(dst + cA) = make_float4(y[0], y[1], y[2], y[3]);
    *reinterpret_cast<float4*>(dst + cB) = make_float4(y[4], y[5], y[6], y[7]);
  }
}

// ---------------- launch ----------------
extern "C" void kernel_launch(void* const* d_in, const int* in_sizes, int n_in,
                              void* d_out, int out_size, void* d_ws, size_t ws_size,
                              hipStream_t stream) {
  const float* z    = (const float*)d_in[0];
  const float* P_op = (const float*)d_in[1];
  const float* P_dst= (const float*)d_in[2];
  const float* P_s1 = (const float*)d_in[3];
  const float* P_s2 = (const float*)d_in[4];
  const float* P_imm= (const float*)d_in[5];
  const float* Plen = (const float*)d_in[6];
  const float* W1   = (const float*)d_in[8];
  const float* b1   = (const float*)d_in[9];
  const float* WR   = (const float*)d_in[10];
  const float* bR   = (const float*)d_in[11];
  const float* Wt   = (const float*)d_in[12];
  const float* bt   = (const float*)d_in[13];
  const float* W_r2h= (const float*)d_in[14];
  const float* b_r2h= (const float*)d_in[15];
  const float* ln_g = (const float*)d_in[16];
  const float* ln_b = (const float*)d_in[17];

  const int B = in_sizes[0] / 512;  // 8192
  float* out = (float*)d_out;
  float* part    = out + (size_t)(1 << 25);            // 8 * B*128 f32 K-split partials (read before expand writes)
  float* thr_out = out + (size_t)B * 16 * 512;         // threshold output region

  float* ws = (float*)d_ws;
  float* prog   = ws;                                  // B*16*5
  float* plen   = prog + (size_t)B * 80;               // B
  float* Rfinal = plen + B;                            // B*16*8
  float* thr_part = Rfinal + (size_t)B * 128;          // 8 * B
  unsigned short* W1t = (unsigned short*)(thr_part + (size_t)8 * B);  // 1024x512 bf16
  unsigned short* WRt = W1t + (size_t)1024 * 512;                     // 128x1024 bf16
  unsigned short* zb  = WRt + (size_t)128 * 1024;                     // B*512 bf16

  const dim3 blk(256);
  prep_kernel<<<dim3(3200), blk, 0, stream>>>(z, zb, B * 512 / 8, W1, WR, W1t, WRt,
                                              P_op, P_dst, P_s1, P_s2, P_imm, Plen,
                                              prog, plen, B * 16);
  gemm_fused<<<dim3(512), blk, 0, stream>>>(zb, W1t, b1, WRt, Wt, part, thr_part, B);
  scan2_kernel<<<dim3(B / 16), blk, 0, stream>>>(part, bR, thr_part, bt, prog, plen, Rfinal,
                                                 thr_out, B);
  final_expand2<<<dim3(B * 16 / 4 / 32), blk, 0, stream>>>(Rfinal, W_r2h, b_r2h, ln_g, ln_b, out,
                                                           32);
}

// Round 13
// 109.305 us; speedup vs baseline: 1.0702x; 1.0175x over previous
//
#include <hip/hip_runtime.h>
#include <stdint.h>

typedef __attribute__((ext_vector_type(8))) short short8;
typedef __attribute__((ext_vector_type(4))) float f32x4;
typedef __attribute__((ext_vector_type(8))) unsigned short ushort8;
typedef __attribute__((ext_vector_type(4))) unsigned short ushort4v;

__device__ __forceinline__ unsigned short f2bf(float f) {
  uint32_t u = __float_as_uint(f);
  uint32_t r = (u + 0x7fffu + ((u >> 16) & 1u)) >> 16;  // RNE
  return (unsigned short)r;
}
__device__ __forceinline__ float bf2f(unsigned short v) {
  return __uint_as_float(((uint32_t)v) << 16);
}

typedef __attribute__((address_space(1))) const unsigned int g_u32;
typedef __attribute__((address_space(3))) unsigned int l_u32;
__device__ __forceinline__ void gl_lds16(const void* g, void* l) {
  __builtin_amdgcn_global_load_lds((g_u32*)g, (l_u32*)l, 16, 0, 0);
}

// ---------------- Threefry-2x32-20 (exact JAX partitionable semantics) ----------------
__device__ __forceinline__ uint32_t rotl32(uint32_t v, int d) { return (v << d) | (v >> (32 - d)); }

__device__ __forceinline__ void threefry2x32(uint32_t k0, uint32_t k1, uint32_t& x0, uint32_t& x1) {
  const uint32_t ks2 = k0 ^ k1 ^ 0x1BD11BDAu;
  x0 += k0; x1 += k1;
  x0 += x1; x1 = rotl32(x1, 13); x1 ^= x0;
  x0 += x1; x1 = rotl32(x1, 15); x1 ^= x0;
  x0 += x1; x1 = rotl32(x1, 26); x1 ^= x0;
  x0 += x1; x1 = rotl32(x1, 6);  x1 ^= x0;
  x0 += k1; x1 += ks2 + 1u;
  x0 += x1; x1 = rotl32(x1, 17); x1 ^= x0;
  x0 += x1; x1 = rotl32(x1, 29); x1 ^= x0;
  x0 += x1; x1 = rotl32(x1, 16); x1 ^= x0;
  x0 += x1; x1 = rotl32(x1, 24); x1 ^= x0;
  x0 += ks2; x1 += k0 + 2u;
  x0 += x1; x1 = rotl32(x1, 13); x1 ^= x0;
  x0 += x1; x1 = rotl32(x1, 15); x1 ^= x0;
  x0 += x1; x1 = rotl32(x1, 26); x1 ^= x0;
  x0 += x1; x1 = rotl32(x1, 6);  x1 ^= x0;
  x0 += k0; x1 += k1 + 3u;
  x0 += x1; x1 = rotl32(x1, 17); x1 ^= x0;
  x0 += x1; x1 = rotl32(x1, 29); x1 ^= x0;
  x0 += x1; x1 = rotl32(x1, 16); x1 ^= x0;
  x0 += x1; x1 = rotl32(x1, 24); x1 ^= x0;
  x0 += k1; x1 += ks2 + 4u;
  x0 += x1; x1 = rotl32(x1, 13); x1 ^= x0;
  x0 += x1; x1 = rotl32(x1, 15); x1 ^= x0;
  x0 += x1; x1 = rotl32(x1, 26); x1 ^= x0;
  x0 += x1; x1 = rotl32(x1, 6);  x1 ^= x0;
  x0 += ks2; x1 += k0 + 5u;
}

// ---------------- prep: cast z->bf16 | transpose+cast W1,WR | decode prog ----------------
__global__ __launch_bounds__(256) void prep_kernel(const float* __restrict__ z,
                                                   unsigned short* __restrict__ zb, int n8,
                                                   const float* __restrict__ W1,
                                                   const float* __restrict__ WR,
                                                   unsigned short* __restrict__ W1t,
                                                   unsigned short* __restrict__ WRt,
                                                   const float* __restrict__ P_op,
                                                   const float* __restrict__ P_dst,
                                                   const float* __restrict__ P_s1,
                                                   const float* __restrict__ P_s2,
                                                   const float* __restrict__ P_imm,
                                                   const float* __restrict__ Plen,
                                                   float* __restrict__ prog,
                                                   float* __restrict__ plen, int BT) {
  __shared__ float t[32][33];
  const int tid = threadIdx.x;
  const int bx = blockIdx.x;
  if (bx < 2048) {                       // ---- cast z -> bf16 ----
    const int i = bx * 256 + tid;
    if (i >= n8) return;
    const float4 a = reinterpret_cast<const float4*>(z)[i * 2];
    const float4 b = reinterpret_cast<const float4*>(z)[i * 2 + 1];
    ushort8 u;
    u[0] = f2bf(a.x); u[1] = f2bf(a.y); u[2] = f2bf(a.z); u[3] = f2bf(a.w);
    u[4] = f2bf(b.x); u[5] = f2bf(b.y); u[6] = f2bf(b.z); u[7] = f2bf(b.w);
    reinterpret_cast<ushort8*>(zb)[i] = u;
  } else if (bx < 2688) {                // ---- transpose + cast weights ----
    const int b = bx - 2048;
    const float* src; unsigned short* dst; int N, K, k0, n0;
    if (b < 512) {
      src = W1; dst = W1t; N = 1024; K = 512;
      k0 = (b & 15) * 32; n0 = (b >> 4) * 32;
    } else {
      const int b2 = b - 512;
      src = WR; dst = WRt; N = 128; K = 1024;
      k0 = (b2 & 31) * 32; n0 = (b2 >> 5) * 32;
    }
    {
      const int row = tid >> 3, c4 = (tid & 7) * 4;
      const float4 v = *reinterpret_cast<const float4*>(&src[(size_t)(k0 + row) * N + n0 + c4]);
      t[row][c4] = v.x; t[row][c4 + 1] = v.y; t[row][c4 + 2] = v.z; t[row][c4 + 3] = v.w;
    }
    __syncthreads();
    {
      const int n = tid >> 3, k4 = (tid & 7) * 4;
      ushort4v o;
      o.x = f2bf(t[k4 + 0][n]); o.y = f2bf(t[k4 + 1][n]);
      o.z = f2bf(t[k4 + 2][n]); o.w = f2bf(t[k4 + 3][n]);
      *reinterpret_cast<ushort4v*>(&dst[(size_t)(n0 + n) * K + k0 + k4]) = o;
    }
  } else {                               // ---- decode prog ----
    const int i = (bx - 2688) * 256 + tid;
    if (i >= BT) return;
    const float* po = P_op + (size_t)i * 4;
    const float op = po[0] + 2.f * po[1] + 4.f * po[2] + 8.f * po[3];
    const float* pd = P_dst + (size_t)i * 3;
    const float dv = pd[0] + 2.f * pd[1] + 4.f * pd[2];
    const float* p1 = P_s1 + (size_t)i * 3;
    const float s1v = p1[0] + 2.f * p1[1] + 4.f * p1[2];
    const float* p2 = P_s2 + (size_t)i * 3;
    const float s2v = p2[0] + 2.f * p2[1] + 4.f * p2[2];
    const float* pi = P_imm + (size_t)i * 3;
    const float imv = pi[0] + 2.f * pi[1] + 4.f * pi[2];
    float* o = prog + (size_t)i * 5;
    o[0] = op; o[1] = dv; o[2] = s1v; o[3] = s2v; o[4] = imv;
    if ((i & 15) == 0) {
      const int b = i >> 4;
      const float* pl = Plen + (size_t)b * 4;
      plen[b] = pl[0] + 2.f * pl[1] + 4.f * pl[2] + 8.f * pl[3];
    }
  }
}

// ---------------- fused GEMM1 + GEMM2-slice + threshold-slice, XCD-swizzled grid ----------------
__global__ __launch_bounds__(256) void gemm_fused(const unsigned short* __restrict__ zb,
                                                  const unsigned short* __restrict__ W1t,
                                                  const float* __restrict__ b1,
                                                  const unsigned short* __restrict__ WRt,
                                                  const float* __restrict__ Wt,
                                                  float* __restrict__ part,
                                                  float* __restrict__ thr_part, int B) {
  __shared__ __align__(16) char smem[34816];
  unsigned short* AsF = (unsigned short*)smem;            // phase 1: [128][64] swizzled
  unsigned short* BsF = (unsigned short*)(smem + 16384);  // phase 1: [128][64] swizzled
  auto H2 = reinterpret_cast<unsigned short (*)[136]>(smem);  // phase 2/3: [128][136]

  const int tid = threadIdx.x;
  const int lane = tid & 63, wave = tid >> 6;
  const int wm = wave >> 1, wn = wave & 1;
  const int wgid = blockIdx.x;                  // 0..511
  const int work = (wgid & 7) * 64 + (wgid >> 3);
  const int by = work >> 3, bx = work & 7;
  const int bm = by * 128, bn = bx * 128;

  f32x4 acc[4][4];
#pragma unroll
  for (int i = 0; i < 4; ++i)
#pragma unroll
    for (int j = 0; j < 4; ++j) acc[i][j] = (f32x4)0.f;

  const int fr = lane & 15, kc = (lane >> 4) * 8;
  const int lr = (lane >> 4) * 4, lc = lane & 15;
  const int lrow = lane >> 3, slot = lane & 7;
  const int sslot = (slot ^ lrow) << 3;
  const int fx = fr & 7;
  const int cbase = lane >> 4;

  // ---- phase 1: GEMM1 over K=512, BK=64, async staging ----
  for (int k0 = 0; k0 < 512; k0 += 64) {
#pragma unroll
    for (int i = 0; i < 4; ++i) {
      const int r0 = wave * 32 + i * 8;
      gl_lds16(&zb[(size_t)(bm + r0 + lrow) * 512 + k0 + sslot], &AsF[r0 * 64]);
    }
#pragma unroll
    for (int i = 0; i < 4; ++i) {
      const int r0 = wave * 32 + i * 8;
      gl_lds16(&W1t[(size_t)(bn + r0 + lrow) * 512 + k0 + sslot], &BsF[r0 * 64]);
    }
    __syncthreads();
#pragma unroll
    for (int s = 0; s < 2; ++s) {
      short8 af[4], bfv[4];
#pragma unroll
      for (int f = 0; f < 4; ++f) {
        const int row = wm * 64 + f * 16 + fr;
        const int c = s * 4 + cbase;
        af[f] = *reinterpret_cast<const short8*>(&AsF[row * 64 + ((c ^ fx) << 3)]);
      }
#pragma unroll
      for (int f = 0; f < 4; ++f) {
        const int row = wn * 64 + f * 16 + fr;
        const int c = s * 4 + cbase;
        bfv[f] = *reinterpret_cast<const short8*>(&BsF[row * 64 + ((c ^ fx) << 3)]);
      }
#pragma unroll
      for (int fm = 0; fm < 4; ++fm)
#pragma unroll
        for (int fn = 0; fn < 4; ++fn)
          acc[fm][fn] = __builtin_amdgcn_mfma_f32_16x16x32_bf16(af[fm], bfv[fn], acc[fm][fn], 0, 0, 0);
    }
    __syncthreads();
  }

  // ---- epilogue: h_tile = relu(acc + b1) bf16 -> LDS H2 ----
#pragma unroll
  for (int fn = 0; fn < 4; ++fn) {
    const int col_l = wn * 64 + fn * 16 + lc;
    const float bv = b1[bn + col_l];
#pragma unroll
    for (int fm = 0; fm < 4; ++fm) {
      const int row_l0 = wm * 64 + fm * 16 + lr;
#pragma unroll
      for (int r = 0; r < 4; ++r)
        H2[row_l0 + r][col_l] = f2bf(fmaxf(acc[fm][fn][r] + bv, 0.f));
    }
  }
  __syncthreads();

  // ---- phase 3: threshold partial ----
  {
    const int row = tid >> 1, half = tid & 1;
    const unsigned short* hp = &H2[row][half * 64];
    const float* wp = &Wt[bn + half * 64];
    float s = 0.f;
#pragma unroll
    for (int j = 0; j < 8; ++j) {
      const ushort8 a = *reinterpret_cast<const ushort8*>(hp + j * 8);
      const float4 w0 = *reinterpret_cast<const float4*>(wp + j * 8);
      const float4 w1 = *reinterpret_cast<const float4*>(wp + j * 8 + 4);
      s += bf2f(a[0]) * w0.x + bf2f(a[1]) * w0.y + bf2f(a[2]) * w0.z + bf2f(a[3]) * w0.w;
      s += bf2f(a[4]) * w1.x + bf2f(a[5]) * w1.y + bf2f(a[6]) * w1.z + bf2f(a[7]) * w1.w;
    }
    s += __shfl_xor(s, 1);
    if (half == 0) thr_part[(size_t)bx * B + bm + row] = s;
  }

  // ---- phase 2: GEMM2 slice ----
  f32x4 acc2[4][4];
#pragma unroll
  for (int i = 0; i < 4; ++i)
#pragma unroll
    for (int j = 0; j < 4; ++j) acc2[i][j] = (f32x4)0.f;

#pragma unroll
  for (int ks = 0; ks < 4; ++ks) {
    short8 af2[4], bf2v[4];
#pragma unroll
    for (int fm = 0; fm < 4; ++fm)
      af2[fm] = *reinterpret_cast<const short8*>(&H2[wm * 64 + fm * 16 + fr][ks * 32 + kc]);
#pragma unroll
    for (int fn = 0; fn < 4; ++fn)
      bf2v[fn] = *reinterpret_cast<const short8*>(
          &WRt[(size_t)(wn * 64 + fn * 16 + fr) * 1024 + bn + ks * 32 + kc]);
#pragma unroll
    for (int fm = 0; fm < 4; ++fm)
#pragma unroll
      for (int fn = 0; fn < 4; ++fn)
        acc2[fm][fn] = __builtin_amdgcn_mfma_f32_16x16x32_bf16(af2[fm], bf2v[fn], acc2[fm][fn], 0, 0, 0);
  }

  float* pp = part + (size_t)bx * B * 128;
#pragma unroll
  for (int fn = 0; fn < 4; ++fn) {
    const int col = wn * 64 + fn * 16 + lc;
#pragma unroll
    for (int fm = 0; fm < 4; ++fm) {
      const int row0 = bm + wm * 64 + fm * 16 + lr;
#pragma unroll
      for (int r = 0; r < 4; ++r)
        pp[(size_t)(row0 + r) * 128 + col] = acc2[fm][fn][r];
    }
  }
}

// ---------------- fused partial-reduce + sigmoid + soft-VM scan + threshold finish ----------------
__global__ __launch_bounds__(256) void scan2_kernel(const float* __restrict__ part,
                                                    const float* __restrict__ bR,
                                                    const float* __restrict__ thr_part,
                                                    const float* __restrict__ bt,
                                                    const float* __restrict__ prog,
                                                    const float* __restrict__ plen,
                                                    float* __restrict__ Rfinal,
                                                    float* __restrict__ thr_out, int B) {
  __shared__ float s_bits[16][128];
  __shared__ float s_prog[16][80];
  __shared__ float s_plen[16];
  const int tid = threadIdx.x;
  const int b0 = blockIdx.x * 16;
#pragma unroll
  for (int j = 0; j < 8; ++j) {
    const int f = tid + 256 * j;   // 0..2047
    const int lb = f >> 7, c = f & 127;
    float s = part[(size_t)(b0 + lb) * 128 + c];
#pragma unroll
    for (int sl = 1; sl < 8; ++sl)
      s += part[(size_t)sl * B * 128 + (size_t)(b0 + lb) * 128 + c];
    s_bits[lb][c] = 1.f / (1.f + expf(-(s + bR[c])));
  }
#pragma unroll
  for (int j = 0; j < 5; ++j) {
    const int f = tid + 256 * j;
    s_prog[f / 80][f % 80] = prog[(size_t)b0 * 80 + f];
  }
  if (tid < 16) {
    s_plen[tid] = plen[b0 + tid];
    float s = thr_part[b0 + tid];
#pragma unroll
    for (int sl = 1; sl < 8; ++sl) s += thr_part[(size_t)sl * B + b0 + tid];
    thr_out[b0 + tid] = 1.f / (1.f + expf(-(s + bt[0])));
  }
  __syncthreads();

  const int lb = tid >> 4, g = tid & 15;
  const int bg = (b0 + lb) * 16 + g;

  uint32_t k2a, k2b;
  { uint32_t x0 = 0u, x1 = 1u; threefry2x32(0u, 42u, x0, x1); k2a = x0; k2b = x1; }
  uint32_t p0, p1;
  {
    uint32_t x0 = 0u, x1 = (uint32_t)bg * 2u;
    threefry2x32(k2a, k2b, x0, x1);
    p0 = (x0 ^ x1) & 127u;
  }
  {
    uint32_t x0 = 0u, x1 = (uint32_t)bg * 2u + 1u;
    threefry2x32(k2a, k2b, x0, x1);
    p1 = (x0 ^ x1) & 127u;
  }

  float R[8], M[8];
#pragma unroll
  for (int r = 0; r < 8; ++r) {
    float a = 0.f;
#pragma unroll
    for (int bit = 0; bit < 16; ++bit) {
      const int pos = r * 16 + bit;
      float v = s_bits[lb][pos];
      const bool flip = (g != 0) && ((int)p0 == pos || (int)p1 == pos);
      v = flip ? 1.0f - v : v;
      a = fmaf(v, (float)(1 << bit), a);
    }
    R[r] = a;
    M[r] = 0.f;
  }

  const float pl = s_plen[lb];
  for (int t = 0; t < 16; ++t) {
    const float op = s_prog[lb][t * 5 + 0];
    const float dst = s_prog[lb][t * 5 + 1];
    const float sa = s_prog[lb][t * 5 + 2];
    const float sb = s_prog[lb][t * 5 + 3];
    const float imm = s_prog[lb][t * 5 + 4];
    const float active = fminf(fmaxf(pl - (float)t, 0.f), 1.f);
    float r1 = 0.f, r2 = 0.f, m1 = 0.f, old = 0.f;
    float wd[8];
#pragma unroll
    for (int i = 0; i < 8; ++i) {
      const float w1 = fmaxf(1.f - fabsf(sa - (float)i), 0.f);
      const float w2 = fmaxf(1.f - fabsf(sb - (float)i), 0.f);
      wd[i] = fmaxf(1.f - fabsf(dst - (float)i), 0.f);
      r1 = fmaf(w1, R[i], r1);
      r2 = fmaf(w2, R[i], r2);
      m1 = fmaf(w1, M[i], m1);
      old = fmaf(wd[i], R[i], old);
    }
    float results[16];
    results[0] = old;               results[1] = r1 + r2;
    results[2] = r1 - r2;           results[3] = r1 * r2 * (1.f / 65536.f);
    results[4] = r1;                results[5] = imm;
    results[6] = r1 + imm;          results[7] = fmaxf(r1, r2);
    results[8] = fminf(r1, r2);     results[9] = -r1;
    results[10] = 0.5f * r1;        results[11] = r2;
    results[12] = m1;               results[13] = old;
    results[14] = fabsf(r1);        results[15] = old;
    float res = 0.f;
    const float pstore = fmaxf(1.f - fabsf(op - 13.f), 0.f);
#pragma unroll
    for (int o = 0; o < 16; ++o) res = fmaf(fmaxf(1.f - fabsf(op - (float)o), 0.f), results[o], res);
#pragma unroll
    for (int i = 0; i < 8; ++i) {
      R[i] = fmaf(active * wd[i], res - R[i], R[i]);
      M[i] = fmaf(active * pstore * wd[i], r1 - M[i], M[i]);
    }
  }

  float* outp = Rfinal + (size_t)bg * 8;
  *reinterpret_cast<float4*>(outp) = make_float4(R[0], R[1], R[2], R[3]);
  *reinterpret_cast<float4*>(outp + 4) = make_float4(R[4], R[5], R[6], R[7]);
}

// ---------------- expand: coalesced column partition, high-TLP grid (8 rows/wave) ----------------
__global__ __launch_bounds__(256) void final_expand2(const float* __restrict__ Rf,
                                                     const float* __restrict__ W,
                                                     const float* __restrict__ bias,
                                                     const float* __restrict__ gam,
                                                     const float* __restrict__ bet,
                                                     float* __restrict__ out, int rowsPerWave) {
  const int lane = threadIdx.x & 63;
  const int w = blockIdx.x * 4 + (threadIdx.x >> 6);
  const int cA = lane * 4, cB = 256 + lane * 4;   // two contiguous 4-col slices per lane

  float wreg[8][8];   // [reg][j]: j<4 -> col cA+j, j>=4 -> col cB+(j-4)
#pragma unroll
  for (int reg = 0; reg < 8; ++reg) {
    const float4 wa = *reinterpret_cast<const float4*>(&W[reg * 512 + cA]);
    const float4 wb = *reinterpret_cast<const float4*>(&W[reg * 512 + cB]);
    wreg[reg][0] = wa.x; wreg[reg][1] = wa.y; wreg[reg][2] = wa.z; wreg[reg][3] = wa.w;
    wreg[reg][4] = wb.x; wreg[reg][5] = wb.y; wreg[reg][6] = wb.z; wreg[reg][7] = wb.w;
  }
  float bi[8], ga[8], be[8];
  {
    const float4 a = *reinterpret_cast<const float4*>(&bias[cA]);
    const float4 b = *reinterpret_cast<const float4*>(&bias[cB]);
    bi[0] = a.x; bi[1] = a.y; bi[2] = a.z; bi[3] = a.w; bi[4] = b.x; bi[5] = b.y; bi[6] = b.z; bi[7] = b.w;
    const float4 c = *reinterpret_cast<const float4*>(&gam[cA]);
    const float4 d = *reinterpret_cast<const float4*>(&gam[cB]);
    ga[0] = c.x; ga[1] = c.y; ga[2] = c.z; ga[3] = c.w; ga[4] = d.x; ga[5] = d.y; ga[6] = d.z; ga[7] = d.w;
    const float4 e = *reinterpret_cast<const float4*>(&bet[cA]);
    const float4 f = *reinterpret_cast<const float4*>(&bet[cB]);
    be[0] = e.x; be[1] = e.y; be[2] = e.z; be[3] = e.w; be[4] = f.x; be[5] = f.y; be[6] = f.z; be[7] = f.w;
  }

  const int r0 = w * rowsPerWave;
#pragma unroll 2
  for (int i = 0; i < 8; ++i) {
    const int row = r0 + i;
    const float4 ra = *reinterpret_cast<const float4*>(&Rf[(size_t)row * 8]);
    const float4 rb = *reinterpret_cast<const float4*>(&Rf[(size_t)row * 8 + 4]);
    const float r[8] = {ra.x, ra.y, ra.z, ra.w, rb.x, rb.y, rb.z, rb.w};
    float x[8];
#pragma unroll
    for (int j = 0; j < 8; ++j) x[j] = bi[j];
#pragma unroll
    for (int reg = 0; reg < 8; ++reg)
#pragma unroll
      for (int j = 0; j < 8; ++j) x[j] = fmaf(r[reg], wreg[reg][j], x[j]);
    float s1 = 0.f, s2 = 0.f;
#pragma unroll
    for (int j = 0; j < 8; ++j) { s1 += x[j]; s2 = fmaf(x[j], x[j], s2); }
#pragma unroll
    for (int off = 32; off; off >>= 1) { s1 += __shfl_xor(s1, off); s2 += __shfl_xor(s2, off); }
    const float mean = s1 * (1.f / 512.f);
    const float var = s2 * (1.f / 512.f) - mean * mean;
    const float inv = rsqrtf(var + 1e-5f);
    float y[8];
#pragma unroll
    for (int j = 0; j < 8; ++j) y[j] = (x[j] - mean) * inv * ga[j] + be[j];
    float* dst = out + (size_t)row * 512;
    *reinterpret_cast<float4*>(dst + cA) = make_float4(y[0], y[1], y[2], y[3]);
    *reinterpret_cast<float4*>(dst + cB) = make_float4(y[4], y[5], y[6], y[7]);
  }
}

// ---------------- launch ----------------
extern "C" void kernel_launch(void* const* d_in, const int* in_sizes, int n_in,
                              void* d_out, int out_size, void* d_ws, size_t ws_size,
                              hipStream_t stream) {
  const float* z    = (const float*)d_in[0];
  const float* P_op = (const float*)d_in[1];
  const float* P_dst= (const float*)d_in[2];
  const float* P_s1 = (const float*)d_in[3];
  const float* P_s2 = (const float*)d_in[4];
  const float* P_imm= (const float*)d_in[5];
  const float* Plen = (const float*)d_in[6];
  const float* W1   = (const float*)d_in[8];
  const float* b1   = (const float*)d_in[9];
  const float* WR   = (const float*)d_in[10];
  const float* bR   = (const float*)d_in[11];
  const float* Wt   = (const float*)d_in[12];
  const float* bt   = (const float*)d_in[13];
  const float* W_r2h= (const float*)d_in[14];
  const float* b_r2h= (const float*)d_in[15];
  const float* ln_g = (const float*)d_in[16];
  const float* ln_b = (const float*)d_in[17];

  const int B = in_sizes[0] / 512;  // 8192
  float* out = (float*)d_out;
  float* part    = out + (size_t)(1 << 25);            // 8 * B*128 f32 K-split partials (read before expand writes)
  float* thr_out = out + (size_t)B * 16 * 512;         // threshold output region

  float* ws = (float*)d_ws;
  float* prog   = ws;                                  // B*16*5
  float* plen   = prog + (size_t)B * 80;               // B
  float* Rfinal = plen + B;                            // B*16*8
  float* thr_part = Rfinal + (size_t)B * 128;          // 8 * B
  unsigned short* W1t = (unsigned short*)(thr_part + (size_t)8 * B);  // 1024x512 bf16
  unsigned short* WRt = W1t + (size_t)1024 * 512;                     // 128x1024 bf16
  unsigned short* zb  = WRt + (size_t)128 * 1024;                     // B*512 bf16

  const dim3 blk(256);
  prep_kernel<<<dim3(3200), blk, 0, stream>>>(z, zb, B * 512 / 8, W1, WR, W1t, WRt,
                                              P_op, P_dst, P_s1, P_s2, P_imm, Plen,
                                              prog, plen, B * 16);
  gemm_fused<<<dim3(512), blk, 0, stream>>>(zb, W1t, b1, WRt, Wt, part, thr_part, B);
  scan2_kernel<<<dim3(B / 16), blk, 0, stream>>>(part, bR, thr_part, bt, prog, plen, Rfinal,
                                                 thr_out, B);
  final_expand2<<<dim3(B * 16 / 4 / 8), blk, 0, stream>>>(Rfinal, W_r2h, b_r2h, ln_g, ln_b, out,
                                                          8);
}